// Round 3
// baseline (396.572 us; speedup 1.0000x reference)
//
#include <hip/hip_runtime.h>
#include <hip/hip_bf16.h>

#define T_LEN 4096
#define NWIN 31
#define EPS_BN 1e-5f

typedef __attribute__((ext_vector_type(8))) short short8;
typedef __attribute__((ext_vector_type(4))) float f32x4;

__device__ __forceinline__ ushort f2bf(float x) {   // round-to-nearest-even bf16
  unsigned u = __float_as_uint(x);
  return (ushort)((u + 0x7FFFu + ((u >> 16) & 1u)) >> 16);
}
__device__ __forceinline__ float bf2f(ushort h) {
  return __uint_as_float((unsigned)h << 16);
}

// y1g padded rows: 16 front pad + 4096 data + 48 back pad = 4160 rows of
// 128 ushorts (64ch hi/lo, swizzled by (t+15)&15). Pads zeroed in k0.
#define Y1ROWS 4160

// ---------------------------------------------------------------- k0: ALL init
// [0,896) conv-bank frags | [896,960) 1x1 frags | [960,1088) DFT frags |
// 1088 pool coefs | [1089,1729) wp1 frags | [1729,1857) wp2 frags |
// [1857,2369) w_fu frags | [2369,2625) w_out frags | [2625,2657) y1g pad zero
__global__ void k0_all(const float* __restrict__ wt3, const float* __restrict__ wt7,
                       const float* __restrict__ wt15, const float* __restrict__ wt31,
                       const float* __restrict__ w_sp,
                       const float* __restrict__ wp1, const float* __restrict__ wp2,
                       const float* __restrict__ w_fu, const float* __restrict__ w_out,
                       ushort* __restrict__ wfrag, ushort* __restrict__ wfB,
                       ushort* __restrict__ tabf, float4* __restrict__ jc,
                       ushort* __restrict__ wp1f, ushort* __restrict__ wp2f,
                       ushort* __restrict__ wfuf, ushort* __restrict__ woutf,
                       ushort* __restrict__ y1g) {
  int bid = blockIdx.x;
  int tid = threadIdx.x;
  if (bid >= 2625) {                 // zero y1g pad rows (0..15 and 4112..4159)
    int b = bid - 2625;
    unsigned* y1u = (unsigned*)y1g;
    long base = (long)b * Y1ROWS * 64;
#pragma unroll
    for (int it = 0; it < 16; it++) {
      int idx = it * 256 + tid;
      int row = (idx < 1024) ? (idx >> 6) : (4112 + ((idx - 1024) >> 6));
      y1u[base + (long)row * 64 + (idx & 63)] = 0u;
    }
    return;
  }
  if (bid < 896) {
    int e = bid * 256 + tid;
    const float* w; int K, base, eb;
    if (e < 12288)       { w = wt3;  K = 3;  base = 0;   eb = e; }
    else if (e < 40960)  { w = wt7;  K = 7;  base = 48;  eb = e - 12288; }
    else if (e < 102400) { w = wt15; K = 15; base = 160; eb = e - 40960; }
    else                 { w = wt31; K = 31; base = 400; eb = e - 102400; }
    int j = eb / 4096;  int v = eb - j * 4096;
    int ks = v >> 11;   int v2 = v & 2047;
    int tile = v2 >> 9; int wdx = v2 & 511;
    int l = wdx >> 3, i = wdx & 7;
    int o = tile * 16 + (l & 15);
    int c = ks * 32 + 8 * (l >> 4) + i;
    float f = w[(o * 64 + c) * K + j];
    ushort hi = f2bf(f);
    ushort lo = f2bf(f - bf2f(hi));
    int fragp = base + ((j * 2 + ks) * 4 + tile) * 2;
    wfrag[fragp * 512 + wdx] = hi;
    wfrag[(fragp + 1) * 512 + wdx] = lo;
  } else if (bid < 960) {
    int e = (bid - 896) * 256 + tid;
    int frag = e >> 9;
    int wdx = e & 511;
    int l = wdx >> 3, i = wdx & 7;
    int s = frag >> 2, n = frag & 3;
    int c = s * 32 + 8 * (l >> 4) + i;
    int o = n * 16 + (l & 15);
    float f = w_sp[o * 256 + c];
    ushort hi = f2bf(f);
    ushort lo = f2bf(f - bf2f(hi));
    wfB[(frag * 2 + 0) * 512 + wdx] = hi;
    wfB[(frag * 2 + 1) * 512 + wdx] = lo;
  } else if (bid < 1088) {
    int e = (bid - 960) * 256 + tid;
    int fp = e >> 9;
    int wdx = e & 511;
    int l = wdx >> 3, i = wdx & 7;
    int ks = fp >> 3, n = fp & 7;
    int k = ks * 32 + 8 * (l >> 4) + i;
    int fidx = (n & 3) * 16 + (l & 15);
    float v = 0.f;
    if (fidx < 50) {
      int f = fidx + 1;
      int ph = (f * k) & 255;
      float ang = 0.024543692606170259f * (float)ph; // 2*pi/256
      v = (n >= 4) ? sinf(ang) : cosf(ang);
    }
    ushort hi = f2bf(v);
    ushort lo = f2bf(v - bf2f(hi));
    tabf[(fp * 2 + 0) * 512 + wdx] = hi;
    tabf[(fp * 2 + 1) * 512 + wdx] = lo;
  } else if (bid == 1088) {
    if (tid < 128) {
      int l = tid;
      double cc[3] = {0.0, 0.0, 0.0};
      int j0 = -1;
      for (int t = l * 32; t < l * 32 + 32; t++) {
        double src = ((double)t + 0.5) * (31.0 / 4096.0) - 0.5;
        src = src < 0.0 ? 0.0 : (src > 30.0 ? 30.0 : src);
        int i0 = (int)src;
        if (i0 > 30) i0 = 30;
        int i1 = i0 + 1 > 30 ? 30 : i0 + 1;
        double w = src - (double)i0;
        if (j0 < 0) j0 = i0;
        cc[i0 - j0] += 1.0 - w;
        cc[i1 - j0] += w;
      }
      float4 r;
      r.x = __int_as_float(j0);
      r.y = (float)(cc[0] / 32.0);
      r.z = (float)(cc[1] / 32.0);
      r.w = (float)(cc[2] / 32.0);
      jc[l] = r;
    }
  } else if (bid < 1729) {       // wp1 frags: K=1280, N=128, NT=8
    int e = (bid - 1089) * 256 + tid;
    int fp = e >> 9, wdx = e & 511;
    int l = wdx >> 3, i = wdx & 7;
    int ks = fp >> 3, n = fp & 7;
    int k = ks * 32 + 8 * (l >> 4) + i;
    int col = n * 16 + (l & 15);
    float f = wp1[k * 128 + col];
    ushort hi = f2bf(f);
    ushort lo = f2bf(f - bf2f(hi));
    wp1f[(fp * 2 + 0) * 512 + wdx] = hi;
    wp1f[(fp * 2 + 1) * 512 + wdx] = lo;
  } else if (bid < 1857) {       // wp2 frags: K=128, N=256, NT=16
    int e = (bid - 1729) * 256 + tid;
    int fp = e >> 9, wdx = e & 511;
    int l = wdx >> 3, i = wdx & 7;
    int ks = fp >> 4, n = fp & 15;
    int k = ks * 32 + 8 * (l >> 4) + i;
    int col = n * 16 + (l & 15);
    float f = wp2[k * 256 + col];
    ushort hi = f2bf(f);
    ushort lo = f2bf(f - bf2f(hi));
    wp2f[(fp * 2 + 0) * 512 + wdx] = hi;
    wp2f[(fp * 2 + 1) * 512 + wdx] = lo;
  } else if (bid < 2369) {       // w_fu frags: K=512, N=256, NT=16
    int e = (bid - 1857) * 256 + tid;
    int fp = e >> 9, wdx = e & 511;
    int l = wdx >> 3, i = wdx & 7;
    int ks = fp >> 4, n = fp & 15;
    int k = ks * 32 + 8 * (l >> 4) + i;
    int col = n * 16 + (l & 15);
    float f = w_fu[k * 256 + col];
    ushort hi = f2bf(f);
    ushort lo = f2bf(f - bf2f(hi));
    wfuf[(fp * 2 + 0) * 512 + wdx] = hi;
    wfuf[(fp * 2 + 1) * 512 + wdx] = lo;
  } else {                       // w_out frags: K=256, N=256, NT=16
    int e = (bid - 2369) * 256 + tid;
    int fp = e >> 9, wdx = e & 511;
    int l = wdx >> 3, i = wdx & 7;
    int ks = fp >> 4, n = fp & 15;
    int k = ks * 32 + 8 * (l >> 4) + i;
    int col = n * 16 + (l & 15);
    float f = w_out[k * 256 + col];
    ushort hi = f2bf(f);
    ushort lo = f2bf(f - bf2f(hi));
    woutf[(fp * 2 + 0) * 512 + wdx] = hi;
    woutf[(fp * 2 + 1) * 512 + wdx] = lo;
  }
}

// --------------------------------------------- K1: 1x1conv+BN1+ReLU -> y1g (pre-swizzled)
// Each row computed exactly once (no halo). Bit-identical math to the old
// in-k2 staging; output layout = old xs image at global scope:
// row t, channel c: hi at ((c>>3)^s)<<3 | (c&7), lo at (((c>>3)+8)^s)<<3 | (c&7),
// s = (t+15)&15 (block-independent since t0 % 16 == 0).
__launch_bounds__(512)
__global__ void k1_stage(const float* __restrict__ x, const ushort* __restrict__ wfB,
                         const float* __restrict__ b_sp, const float* __restrict__ g1,
                         const float* __restrict__ be1, const float* __restrict__ m1,
                         const float* __restrict__ v1, ushort* __restrict__ y1g) {
  int tid = threadIdx.x;
  int bid = blockIdx.x;
  int b = bid >> 5;
  int t0 = (bid & 31) * 128;
  int l = tid & 63;
  int wid = tid >> 6;
  int lr = l & 15, lg = l >> 4;
  float sbn1[4], cbn1[4];
#pragma unroll
  for (int n = 0; n < 4; n++) {
    int o = n * 16 + lr;
    float s = g1[o] * rsqrtf(v1[o] + EPS_BN);
    sbn1[n] = s;
    cbn1[n] = (b_sp[o] - m1[o]) * s + be1[o];
  }
  const f32x4 z = {0.f, 0.f, 0.f, 0.f};
  int rowbase = wid * 16;
  const float* __restrict__ xp0 = x + ((long)b * T_LEN + t0 + rowbase + lr) * 256 + 8 * lg;
  f32x4 a1x[4];
#pragma unroll
  for (int n = 0; n < 4; n++) a1x[n] = z;
#pragma unroll 2
  for (int s = 0; s < 8; s++) {
    short8 bh[4], bl[4];
#pragma unroll
    for (int n = 0; n < 4; n++) {
      const ushort* bp = wfB + ((s * 4 + n) * 2) * 512 + l * 8;
      bh[n] = *(const short8*)bp;
      bl[n] = *(const short8*)(bp + 512);
    }
    float4 a0 = *(const float4*)(xp0 + s * 32);
    float4 a1 = *(const float4*)(xp0 + s * 32 + 4);
    float av[8] = {a0.x, a0.y, a0.z, a0.w, a1.x, a1.y, a1.z, a1.w};
    short8 ah, al;
#pragma unroll
    for (int i = 0; i < 8; i++) {
      ushort hi = f2bf(av[i]);
      ah[i] = (short)hi;
      al[i] = (short)f2bf(av[i] - bf2f(hi));
    }
#pragma unroll
    for (int n = 0; n < 4; n++) {
      a1x[n] = __builtin_amdgcn_mfma_f32_16x16x32_bf16(ah, bh[n], a1x[n], 0, 0, 0);
      a1x[n] = __builtin_amdgcn_mfma_f32_16x16x32_bf16(al, bh[n], a1x[n], 0, 0, 0);
      a1x[n] = __builtin_amdgcn_mfma_f32_16x16x32_bf16(ah, bl[n], a1x[n], 0, 0, 0);
    }
  }
#pragma unroll
  for (int r = 0; r < 4; r++) {
    int t = t0 + rowbase + lg * 4 + r;
    int sw = (t + 15) & 15;
    long rb = ((long)b * Y1ROWS + 16 + t) * 128;
#pragma unroll
    for (int n = 0; n < 4; n++) {
      float v = fmaxf(fmaf(a1x[n][r], sbn1[n], cbn1[n]), 0.f);
      ushort hi = f2bf(v);
      ushort lo = f2bf(v - bf2f(hi));
      int c = n * 16 + lr;
      int g = c >> 3;
      y1g[rb + (((g ^ sw) << 3) | (c & 7))] = hi;
      y1g[rb + ((((g + 8) ^ sw) << 3) | (c & 7))] = lo;
    }
  }
}

// --------------------------------------------- K2: multi-scale conv (LDS-staged y1)
#define XR2 160   // 128 t-tile + 30 halo rows (+2 load rounding)

__device__ __forceinline__ void conv_accum(
    const ushort* __restrict__ xs, const ushort* __restrict__ wfb,
    int jlo, int jhi, int SH, int h, int l,
    f32x4* __restrict__ acc0, f32x4* __restrict__ acc1) {
  int lr = l & 15, lg = l >> 4;
  int U = (jhi - jlo) * 2;   // u enumerates (j,ks) steps
  short8 c0h, c0l, c1h, c1l;
  {
    const ushort* ap = wfb + (((jlo * 2 + 0) * 4 + h * 2) * 2) * 512 + l * 8;
    c0h = *(const short8*)(ap);
    c0l = *(const short8*)(ap + 512);
    c1h = *(const short8*)(ap + 1024);
    c1l = *(const short8*)(ap + 1536);
  }
#pragma unroll 1
  for (int u = 0; u < U; u++) {
    int un = (u + 1 < U) ? u + 1 : u;
    int jn = jlo + (un >> 1), kn = un & 1;
    const ushort* apn = wfb + (((jn * 2 + kn) * 4 + h * 2) * 2) * 512 + l * 8;
    short8 n0h = *(const short8*)(apn);
    short8 n0l = *(const short8*)(apn + 512);
    short8 n1h = *(const short8*)(apn + 1024);
    short8 n1l = *(const short8*)(apn + 1536);

    int j = jlo + (u >> 1), ks = u & 1;
    int rs = j + SH;
    int gb = ks * 4 + lg;
#pragma unroll
    for (int tt = 0; tt < 8; tt++) {
      int row = tt * 16 + lr + rs;
      int sw = (row & 15) << 3;
      short8 bhi = *(const short8*)&xs[row * 128 + ((gb << 3) ^ sw)];
      short8 blo = *(const short8*)&xs[row * 128 + (((gb + 8) << 3) ^ sw)];
      acc0[tt] = __builtin_amdgcn_mfma_f32_16x16x32_bf16(c0h, bhi, acc0[tt], 0, 0, 0);
      acc0[tt] = __builtin_amdgcn_mfma_f32_16x16x32_bf16(c0h, blo, acc0[tt], 0, 0, 0);
      acc0[tt] = __builtin_amdgcn_mfma_f32_16x16x32_bf16(c0l, bhi, acc0[tt], 0, 0, 0);
      acc1[tt] = __builtin_amdgcn_mfma_f32_16x16x32_bf16(c1h, bhi, acc1[tt], 0, 0, 0);
      acc1[tt] = __builtin_amdgcn_mfma_f32_16x16x32_bf16(c1h, blo, acc1[tt], 0, 0, 0);
      acc1[tt] = __builtin_amdgcn_mfma_f32_16x16x32_bf16(c1l, bhi, acc1[tt], 0, 0, 0);
    }
    c0h = n0h; c0l = n0l; c1h = n1h; c1l = n1l;
  }
}

__device__ __forceinline__ void conv_epilogue(
    const f32x4* __restrict__ acc0, const f32x4* __restrict__ acc1,
    const float* __restrict__ bk, const float* __restrict__ g2,
    const float* __restrict__ be2, const float* __restrict__ m2,
    const float* __restrict__ v2,
    unsigned* __restrict__ y2p, float* __restrict__ pv,
    int b, int t0, int l, int h, int chb) {
  int lr = l & 15, lg = l >> 4;
#pragma unroll
  for (int ti = 0; ti < 2; ti++) {
#pragma unroll
    for (int r = 0; r < 4; r++) {
      int och = chb + h * 32 + ti * 16 + 4 * lg + r;
      float bias = bk[och - chb];
      float s = g2[och] * rsqrtf(v2[och] + EPS_BN);
      float sh = be2[och] - m2[och] * s;
      long idx = ((long)(b * 256 + och)) * T_LEN + t0 + lr;
      float pl[4] = {0.f, 0.f, 0.f, 0.f};
#pragma unroll
      for (int tt = 0; tt < 8; tt++) {
        float a = ti ? acc1[tt][r] : acc0[tt][r];
        float v = fmaf(fmaxf(a + bias, 0.f), s, sh);
        ushort hi = f2bf(v);
        ushort lo = f2bf(v - bf2f(hi));
        y2p[idx + tt * 16] = (unsigned)hi | ((unsigned)lo << 16);
        pl[tt >> 1] += v;
      }
#pragma unroll
      for (int j = 0; j < 4; j++) {
#pragma unroll
        for (int m = 1; m < 16; m <<= 1) pl[j] += __shfl_xor(pl[j], m);
      }
      if (lr == 0) {
#pragma unroll
        for (int j = 0; j < 4; j++)
          pv[((long)(b * 128 + (t0 >> 5) + j)) * 512 + och] = pl[j] * (1.f / 32.f);
      }
    }
  }
}

__launch_bounds__(512, 4)
__global__ void k2_convbank(const ushort* __restrict__ y1g,
    const ushort* __restrict__ wfrag,
    const float* __restrict__ bt3, const float* __restrict__ bt7,
    const float* __restrict__ bt15, const float* __restrict__ bt31,
    const float* __restrict__ g2, const float* __restrict__ be2,
    const float* __restrict__ m2, const float* __restrict__ v2,
    unsigned* __restrict__ y2p, float* __restrict__ pv) {
  __shared__ __align__(16) ushort xs[XR2 * 128];   // staged tile; reused as f32x4 red[]
  int tid = threadIdx.x;
  int bid = blockIdx.x;
  int b = bid >> 5;
  int t0 = (bid & 31) * 128;
  int l = tid & 63;
  int wid = __builtin_amdgcn_readfirstlane(tid >> 6);

  // ---- staging: 160 rows (t0-15 .. t0+144) from pre-swizzled y1g.
  // LDS row r <-> padded row t0+1+r; 1 KB per instr, 5 per wave.
  {
    long gb = ((long)b * Y1ROWS + t0 + 1) * 128;
    const ushort* gpw = y1g + gb + (long)(wid * 20) * 128;
    int lo = ((l >> 4) * 128 + (l & 15) * 8);
    uint4 v[5];
#pragma unroll
    for (int i = 0; i < 5; i++)
      v[i] = *(const uint4*)(gpw + i * 512 + lo);
#pragma unroll
    for (int i = 0; i < 5; i++)
      *(uint4*)&xs[(wid * 5 + i) * 512 + l * 8] = v[i];
  }
  __syncthreads();

  // ---- conv phase
  int beta, h, jlo, jhi, role, slot;   // role: 0 direct, 1 flush, 2 add
  switch (wid) {
    case 0:  beta = 3; h = 0; jlo = 0;  jhi = 16; role = 2; slot = 0; break;
    case 1:  beta = 3; h = 0; jlo = 16; jhi = 31; role = 1; slot = 0; break;
    case 2:  beta = 3; h = 1; jlo = 0;  jhi = 16; role = 2; slot = 1; break;
    case 3:  beta = 3; h = 1; jlo = 16; jhi = 31; role = 1; slot = 1; break;
    case 4:  beta = 2; h = 0; jlo = 0;  jhi = 15; role = 0; slot = 0; break;
    case 5:  beta = 2; h = 1; jlo = 0;  jhi = 15; role = 0; slot = 0; break;
    case 6:  beta = 1; h = 0; jlo = 0;  jhi = 7;  role = 0; slot = 0; break;
    default: beta = 1; h = 1; jlo = 0;  jhi = 7;  role = 0; slot = 0; break;
  }
  const int FB[4]  = {0, 48, 160, 400};
  const int SHs[4] = {14, 12, 8, 0};
  const int CHB[4] = {0, 64, 128, 192};
  const float* bk = (beta == 0) ? bt3 : (beta == 1) ? bt7 : (beta == 2) ? bt15 : bt31;

  f32x4 acc0[8], acc1[8];
  const f32x4 z = {0.f, 0.f, 0.f, 0.f};
#pragma unroll
  for (int tt = 0; tt < 8; tt++) { acc0[tt] = z; acc1[tt] = z; }

  conv_accum(xs, wfrag + FB[beta] * 512, jlo, jhi, SHs[beta], h, l, acc0, acc1);
  if (role == 0) {
    conv_epilogue(acc0, acc1, bk, g2, be2, m2, v2, y2p, pv, b, t0, l, h, CHB[beta]);
    if (wid >= 6) {   // second pass: K=3 branch on same half
#pragma unroll
      for (int tt = 0; tt < 8; tt++) { acc0[tt] = z; acc1[tt] = z; }
      conv_accum(xs, wfrag, 0, 3, 14, h, l, acc0, acc1);
      conv_epilogue(acc0, acc1, bt3, g2, be2, m2, v2, y2p, pv, b, t0, l, h, 0);
    }
  }
  __syncthreads();                       // xs reads complete everywhere
  f32x4* red = (f32x4*)xs;
  if (role == 1) {
    f32x4* rp = red + (slot * 64 + l) * 16;
#pragma unroll
    for (int tt = 0; tt < 8; tt++) {
      rp[(tt * 2 + 0) ^ (l & 15)] = acc0[tt];
      rp[(tt * 2 + 1) ^ (l & 15)] = acc1[tt];
    }
  }
  __syncthreads();
  if (role == 2) {
    const f32x4* rp = red + (slot * 64 + l) * 16;
#pragma unroll
    for (int tt = 0; tt < 8; tt++) {
      acc0[tt] += rp[(tt * 2 + 0) ^ (l & 15)];
      acc1[tt] += rp[(tt * 2 + 1) ^ (l & 15)];
    }
    conv_epilogue(acc0, acc1, bt31, g2, be2, m2, v2, y2p, pv, b, t0, l, h, 192);
  }
}

// --------------------------------------------- K3: windowed DFT powers via MFMA
__launch_bounds__(512)
__global__ void k3_spectral(const unsigned* __restrict__ y2p,
                            const ushort* __restrict__ tabf, float* __restrict__ h0) {
  int tid = threadIdx.x;
  int l = tid & 63;
  int wid = tid >> 6;            // wave owns ch 32*wid .. +31 (2 M-tiles)
  int bid = (int)(blockIdx.x % 8u) * 124 + (int)(blockIdx.x / 8u);
  int win = bid % NWIN;
  int b = bid / NWIN;
  int t0 = win * 128;
  int lr = l & 15, lg = l >> 4;
  f32x4 acc[2][8];
  const f32x4 z = {0.f, 0.f, 0.f, 0.f};
#pragma unroll
  for (int mt = 0; mt < 2; mt++)
#pragma unroll
    for (int n = 0; n < 8; n++) acc[mt][n] = z;
  long abase = ((long)(b * 256 + wid * 32 + lr)) * T_LEN + t0 + 8 * lg;
  const unsigned* __restrict__ xp = y2p + abase;
  uint4 cA0[2], cA1[2];
#pragma unroll
  for (int mt = 0; mt < 2; mt++) {
    const uint4* p = (const uint4*)(xp + (long)mt * 16 * T_LEN);
    cA0[mt] = p[0];
    cA1[mt] = p[1];
  }
#pragma unroll 1
  for (int ks = 0; ks < 8; ks++) {
    uint4 nA0[2], nA1[2];
    if (ks < 7) {
#pragma unroll
      for (int mt = 0; mt < 2; mt++) {
        const uint4* p = (const uint4*)(xp + (long)mt * 16 * T_LEN + (ks + 1) * 32);
        nA0[mt] = p[0];
        nA1[mt] = p[1];
      }
    } else {
#pragma unroll
      for (int mt = 0; mt < 2; mt++) { nA0[mt] = cA0[mt]; nA1[mt] = cA1[mt]; }
    }
    short8 ah[2], al[2];
#pragma unroll
    for (int mt = 0; mt < 2; mt++) {
      unsigned vv[8] = {cA0[mt].x, cA0[mt].y, cA0[mt].z, cA0[mt].w,
                        cA1[mt].x, cA1[mt].y, cA1[mt].z, cA1[mt].w};
#pragma unroll
      for (int i = 0; i < 8; i++) {
        ah[mt][i] = (short)(vv[i] & 0xffffu);
        al[mt][i] = (short)(vv[i] >> 16);
      }
    }
#pragma unroll
    for (int n = 0; n < 8; n++) {
      const ushort* bp = tabf + ((ks * 8 + n) * 2) * 512 + l * 8;
      short8 bh = *(const short8*)bp;
      short8 bl = *(const short8*)(bp + 512);
#pragma unroll
      for (int mt = 0; mt < 2; mt++) {
        acc[mt][n] = __builtin_amdgcn_mfma_f32_16x16x32_bf16(ah[mt], bh, acc[mt][n], 0, 0, 0);
        acc[mt][n] = __builtin_amdgcn_mfma_f32_16x16x32_bf16(al[mt], bh, acc[mt][n], 0, 0, 0);
        acc[mt][n] = __builtin_amdgcn_mfma_f32_16x16x32_bf16(ah[mt], bl, acc[mt][n], 0, 0, 0);
      }
    }
#pragma unroll
    for (int mt = 0; mt < 2; mt++) { cA0[mt] = nA0[mt]; cA1[mt] = nA1[mt]; }
  }
  float wt[4][5];
#pragma unroll
  for (int n = 0; n < 4; n++) {
    int f = n * 16 + lr;
    wt[n][0] = (f <= 3)            ? 0.25f        : 0.f;
    wt[n][1] = (f >= 3 && f <= 7)  ? 0.2f         : 0.f;
    wt[n][2] = (f >= 7 && f <= 12) ? (1.f / 6.f)  : 0.f;
    wt[n][3] = (f >= 12 && f <= 29)? (1.f / 18.f) : 0.f;
    wt[n][4] = (f >= 29 && f <= 49)? (1.f / 21.f) : 0.f;
  }
  long hb = ((long)(b * NWIN + win)) * 1280;
#pragma unroll
  for (int mt = 0; mt < 2; mt++) {
#pragma unroll
    for (int r = 0; r < 4; r++) {
      float p0, p1, p2, p3;
      { float re = acc[mt][0][r], im = acc[mt][4][r]; p0 = re * re + im * im; }
      { float re = acc[mt][1][r], im = acc[mt][5][r]; p1 = re * re + im * im; }
      { float re = acc[mt][2][r], im = acc[mt][6][r]; p2 = re * re + im * im; }
      { float re = acc[mt][3][r], im = acc[mt][7][r]; p3 = re * re + im * im; }
      float s0 = p0 * wt[0][0] + p1 * wt[1][0] + p2 * wt[2][0] + p3 * wt[3][0];
      float s1 = p0 * wt[0][1] + p1 * wt[1][1] + p2 * wt[2][1] + p3 * wt[3][1];
      float s2 = p0 * wt[0][2] + p1 * wt[1][2] + p2 * wt[2][2] + p3 * wt[3][2];
      float s3 = p0 * wt[0][3] + p1 * wt[1][3] + p2 * wt[2][3] + p3 * wt[3][3];
      float s4 = p0 * wt[0][4] + p1 * wt[1][4] + p2 * wt[2][4] + p3 * wt[3][4];
#pragma unroll
      for (int m = 1; m < 16; m <<= 1) {
        s0 += __shfl_xor(s0, m);
        s1 += __shfl_xor(s1, m);
        s2 += __shfl_xor(s2, m);
        s3 += __shfl_xor(s3, m);
        s4 += __shfl_xor(s4, m);
      }
      if (lr < 5) {
        float out = lr == 0 ? s0 : lr == 1 ? s1 : lr == 2 ? s2 : lr == 3 ? s3 : s4;
        int ch = wid * 32 + mt * 16 + lg * 4 + r;
        h0[hb + lr * 256 + ch] = out;
      }
    }
  }
}

// --------------------------------------------- K4: spectral MLP via MFMA
// Block = 16 rows, 4 waves = n-quarters. Layer1 K=1280, layer2 K=128.
__launch_bounds__(256)
__global__ void k4_mlp(const float* __restrict__ h0, const ushort* __restrict__ wp1f,
                       const float* __restrict__ bp1, const ushort* __restrict__ wp2f,
                       const float* __restrict__ bp2, float* __restrict__ hs) {
  __shared__ ushort t1h[16][136];
  __shared__ ushort t1l[16][136];
  int tid = threadIdx.x;
  int l = tid & 63, wid = tid >> 6;
  int lr = l & 15, lg = l >> 4;
  int r0 = blockIdx.x * 16;
  const float* __restrict__ ap0 = h0 + (long)(r0 + lr) * 1280 + 8 * lg;
  const f32x4 z = {0.f, 0.f, 0.f, 0.f};
  f32x4 acc[2];
  acc[0] = z; acc[1] = z;
#pragma unroll 2
  for (int ks = 0; ks < 40; ks++) {
    float4 a0 = *(const float4*)(ap0 + ks * 32);
    float4 a1 = *(const float4*)(ap0 + ks * 32 + 4);
    float av[8] = {a0.x, a0.y, a0.z, a0.w, a1.x, a1.y, a1.z, a1.w};
    short8 ah, al;
#pragma unroll
    for (int i = 0; i < 8; i++) {
      ushort hi = f2bf(av[i]);
      ah[i] = (short)hi;
      al[i] = (short)f2bf(av[i] - bf2f(hi));
    }
#pragma unroll
    for (int nt = 0; nt < 2; nt++) {
      const ushort* bp = wp1f + ((ks * 8 + wid * 2 + nt) * 2) * 512 + l * 8;
      short8 bh = *(const short8*)bp;
      short8 bl = *(const short8*)(bp + 512);
      acc[nt] = __builtin_amdgcn_mfma_f32_16x16x32_bf16(ah, bh, acc[nt], 0, 0, 0);
      acc[nt] = __builtin_amdgcn_mfma_f32_16x16x32_bf16(al, bh, acc[nt], 0, 0, 0);
      acc[nt] = __builtin_amdgcn_mfma_f32_16x16x32_bf16(ah, bl, acc[nt], 0, 0, 0);
    }
  }
#pragma unroll
  for (int nt = 0; nt < 2; nt++) {
    int col = (wid * 2 + nt) * 16 + lr;
    float bb = bp1[col];
#pragma unroll
    for (int r = 0; r < 4; r++) {
      int row = lg * 4 + r;
      float v = fmaxf(acc[nt][r] + bb, 0.f);
      ushort hi = f2bf(v);
      ushort lo = f2bf(v - bf2f(hi));
      t1h[row][col] = hi;
      t1l[row][col] = lo;
    }
  }
  __syncthreads();
  f32x4 a2[4];
#pragma unroll
  for (int nt = 0; nt < 4; nt++) a2[nt] = z;
#pragma unroll
  for (int ks = 0; ks < 4; ks++) {
    short8 ah = *(const short8*)&t1h[lr][ks * 32 + 8 * lg];
    short8 al = *(const short8*)&t1l[lr][ks * 32 + 8 * lg];
#pragma unroll
    for (int nt = 0; nt < 4; nt++) {
      const ushort* bp = wp2f + ((ks * 16 + wid * 4 + nt) * 2) * 512 + l * 8;
      short8 bh = *(const short8*)bp;
      short8 bl = *(const short8*)(bp + 512);
      a2[nt] = __builtin_amdgcn_mfma_f32_16x16x32_bf16(ah, bh, a2[nt], 0, 0, 0);
      a2[nt] = __builtin_amdgcn_mfma_f32_16x16x32_bf16(al, bh, a2[nt], 0, 0, 0);
      a2[nt] = __builtin_amdgcn_mfma_f32_16x16x32_bf16(ah, bl, a2[nt], 0, 0, 0);
    }
  }
#pragma unroll
  for (int nt = 0; nt < 4; nt++) {
    int col = (wid * 4 + nt) * 16 + lr;
    float bb = bp2[col];
#pragma unroll
    for (int r = 0; r < 4; r++) {
      long row = r0 + lg * 4 + r;
      hs[row * 256 + col] = a2[nt][r] + bb;
    }
  }
}

// --------------------------------------------- K5a: spec interp (3-coef) -> pv
__launch_bounds__(256)
__global__ void k5a_spec(const float* __restrict__ hs, const float4* __restrict__ jc,
                         float* __restrict__ pv) {
  int o = threadIdx.x;
  int l = blockIdx.x & 127, b = blockIdx.x >> 7;
  float4 c = jc[l];
  int j0 = __float_as_int(c.x);
  const float* __restrict__ hb = hs + (long)b * NWIN * 256;
  int i0 = j0 > 30 ? 30 : j0;
  int i1 = j0 + 1 > 30 ? 30 : j0 + 1;
  int i2 = j0 + 2 > 30 ? 30 : j0 + 2;
  float v = c.y * hb[i0 * 256 + o] + c.z * hb[i1 * 256 + o] + c.w * hb[i2 * 256 + o];
  pv[((long)(b * 128 + l)) * 512 + 256 + o] = v;
}

// --------------------------------------------- K5b: fused proj + pos + out proj via MFMA
// Block = 32 rows (2 M-tiles), 4 waves = (m-tile, n-half). K=512 then K=256.
__launch_bounds__(256)
__global__ void k5b_out(const float* __restrict__ pv, const ushort* __restrict__ wfuf,
                        const float* __restrict__ b_fu, const float* __restrict__ pos,
                        const ushort* __restrict__ woutf, const float* __restrict__ b_out,
                        float* __restrict__ out) {
  __shared__ ushort gh[32][264];
  __shared__ ushort gl[32][264];
  int tid = threadIdx.x;
  int l = tid & 63, wid = tid >> 6;
  int lr = l & 15, lg = l >> 4;
  int mt = wid & 1, nh = wid >> 1;
  int r0 = blockIdx.x * 32;
  int lbase = r0 & 127;
  const float* __restrict__ ap0 = pv + (long)(r0 + mt * 16 + lr) * 512 + 8 * lg;
  const f32x4 z = {0.f, 0.f, 0.f, 0.f};
  f32x4 acc[8];
#pragma unroll
  for (int nt = 0; nt < 8; nt++) acc[nt] = z;
#pragma unroll 1
  for (int ks = 0; ks < 16; ks++) {
    float4 a0 = *(const float4*)(ap0 + ks * 32);
    float4 a1 = *(const float4*)(ap0 + ks * 32 + 4);
    float av[8] = {a0.x, a0.y, a0.z, a0.w, a1.x, a1.y, a1.z, a1.w};
    short8 ah, al;
#pragma unroll
    for (int i = 0; i < 8; i++) {
      ushort hi = f2bf(av[i]);
      ah[i] = (short)hi;
      al[i] = (short)f2bf(av[i] - bf2f(hi));
    }
#pragma unroll
    for (int nt = 0; nt < 8; nt++) {
      const ushort* bp = wfuf + ((ks * 16 + nh * 8 + nt) * 2) * 512 + l * 8;
      short8 bh = *(const short8*)bp;
      short8 bl = *(const short8*)(bp + 512);
      acc[nt] = __builtin_amdgcn_mfma_f32_16x16x32_bf16(ah, bh, acc[nt], 0, 0, 0);
      acc[nt] = __builtin_amdgcn_mfma_f32_16x16x32_bf16(al, bh, acc[nt], 0, 0, 0);
      acc[nt] = __builtin_amdgcn_mfma_f32_16x16x32_bf16(ah, bl, acc[nt], 0, 0, 0);
    }
  }
#pragma unroll
  for (int nt = 0; nt < 8; nt++) {
    int col = (nh * 8 + nt) * 16 + lr;
    float bb = b_fu[col];
#pragma unroll
    for (int r = 0; r < 4; r++) {
      int row = mt * 16 + lg * 4 + r;
      float v = acc[nt][r] + bb + pos[(lbase + row) * 256 + col];
      ushort hi = f2bf(v);
      ushort lo = f2bf(v - bf2f(hi));
      gh[row][col] = hi;
      gl[row][col] = lo;
    }
  }
  __syncthreads();
  f32x4 a2[8];
#pragma unroll
  for (int nt = 0; nt < 8; nt++) a2[nt] = z;
#pragma unroll 1
  for (int ks = 0; ks < 8; ks++) {
    short8 ah = *(const short8*)&gh[mt * 16 + lr][ks * 32 + 8 * lg];
    short8 al = *(const short8*)&gl[mt * 16 + lr][ks * 32 + 8 * lg];
#pragma unroll
    for (int nt = 0; nt < 8; nt++) {
      const ushort* bp = woutf + ((ks * 16 + nh * 8 + nt) * 2) * 512 + l * 8;
      short8 bh = *(const short8*)bp;
      short8 bl = *(const short8*)(bp + 512);
      a2[nt] = __builtin_amdgcn_mfma_f32_16x16x32_bf16(ah, bh, a2[nt], 0, 0, 0);
      a2[nt] = __builtin_amdgcn_mfma_f32_16x16x32_bf16(al, bh, a2[nt], 0, 0, 0);
      a2[nt] = __builtin_amdgcn_mfma_f32_16x16x32_bf16(ah, bl, a2[nt], 0, 0, 0);
    }
  }
#pragma unroll
  for (int nt = 0; nt < 8; nt++) {
    int col = (nh * 8 + nt) * 16 + lr;
    float bb = b_out[col];
#pragma unroll
    for (int r = 0; r < 4; r++) {
      long row = r0 + mt * 16 + lg * 4 + r;
      out[row * 256 + col] = a2[nt][r] + bb;
    }
  }
}

// ---------------------------------------------------------------- launcher
extern "C" void kernel_launch(void* const* d_in, const int* in_sizes, int n_in,
                              void* d_out, int out_size, void* d_ws, size_t ws_size,
                              hipStream_t stream) {
  const float* x    = (const float*)d_in[0];
  const float* w_sp = (const float*)d_in[1];
  const float* b_sp = (const float*)d_in[2];
  const float* g1   = (const float*)d_in[3];
  const float* be1  = (const float*)d_in[4];
  const float* m1   = (const float*)d_in[5];
  const float* v1   = (const float*)d_in[6];
  const float* wt3  = (const float*)d_in[7];
  const float* bt3  = (const float*)d_in[8];
  const float* wt7  = (const float*)d_in[9];
  const float* bt7  = (const float*)d_in[10];
  const float* wt15 = (const float*)d_in[11];
  const float* bt15 = (const float*)d_in[12];
  const float* wt31 = (const float*)d_in[13];
  const float* bt31 = (const float*)d_in[14];
  const float* g2   = (const float*)d_in[15];
  const float* be2  = (const float*)d_in[16];
  const float* m2   = (const float*)d_in[17];
  const float* v2   = (const float*)d_in[18];
  const float* wp1  = (const float*)d_in[19];
  const float* bp1  = (const float*)d_in[20];
  const float* wp2  = (const float*)d_in[21];
  const float* bp2  = (const float*)d_in[22];
  const float* w_fu = (const float*)d_in[23];
  const float* b_fu = (const float*)d_in[24];
  const float* pos  = (const float*)d_in[25];
  const float* w_out= (const float*)d_in[26];
  const float* b_out= (const float*)d_in[27];

  unsigned* y2p = (unsigned*)d_ws;         // 33,554,432 uint (bf16 hi|lo packed)
  float* h0  = (float*)(y2p + 33554432);   //  1,269,760 f32
  float* hs  = h0 + 1269760;               //    253,952
  float* pv  = hs + 253952;                //  2,097,152
  float4* jc = (float4*)(pv + 2097152);    //        128 float4
  ushort* wfrag = (ushort*)(jc + 128);     //    458,752 ushort (conv-bank frags)
  ushort* wfB   = wfrag + 458752;          //     32,768 ushort (1x1 frags)
  ushort* tabf  = wfB + 32768;             //     65,536 ushort (DFT table frags)
  ushort* wp1f  = tabf + 65536;            //    327,680 ushort (wp1 frags)
  ushort* wp2f  = wp1f + 327680;           //     65,536 ushort (wp2 frags)
  ushort* wfuf  = wp2f + 65536;            //    262,144 ushort (w_fu frags)
  ushort* woutf = wfuf + 262144;           //    131,072 ushort (w_out frags)
  ushort* y1g   = woutf + 131072;          // 17,039,360 ushort (padded swizzled y1)

  k0_all<<<2657, 256, 0, stream>>>(wt3, wt7, wt15, wt31, w_sp, wp1, wp2, w_fu, w_out,
                                   wfrag, wfB, tabf, jc, wp1f, wp2f, wfuf, woutf, y1g);
  k1_stage<<<1024, 512, 0, stream>>>(x, wfB, b_sp, g1, be1, m1, v1, y1g);
  k2_convbank<<<1024, 512, 0, stream>>>(y1g, wfrag, bt3, bt7, bt15, bt31,
                                        g2, be2, m2, v2, y2p, pv);
  k3_spectral<<<32 * NWIN, 512, 0, stream>>>(y2p, tabf, h0);
  k4_mlp<<<62, 256, 0, stream>>>(h0, wp1f, bp1, wp2f, bp2, hs);
  k5a_spec<<<32 * 128, 256, 0, stream>>>(hs, jc, pv);
  k5b_out<<<128, 256, 0, stream>>>(pv, wfuf, b_fu, pos, woutf, b_out,
                                   (float*)d_out);
}

// Round 4
// 393.965 us; speedup vs baseline: 1.0066x; 1.0066x over previous
//
#include <hip/hip_runtime.h>
#include <hip/hip_bf16.h>

#define T_LEN 4096
#define NWIN 31
#define EPS_BN 1e-5f

typedef __attribute__((ext_vector_type(8))) short short8;
typedef __attribute__((ext_vector_type(4))) float f32x4;

__device__ __forceinline__ ushort f2bf(float x) {   // round-to-nearest-even bf16
  unsigned u = __float_as_uint(x);
  return (ushort)((u + 0x7FFFu + ((u >> 16) & 1u)) >> 16);
}
__device__ __forceinline__ float bf2f(ushort h) {
  return __uint_as_float((unsigned)h << 16);
}

// y1g padded rows: 16 front pad + 4096 data + 48 back pad = 4160 rows of
// 128 ushorts (64ch hi/lo, swizzled by (t+15)&15). Pads zeroed in k0.
#define Y1ROWS 4160

// ---------------------------------------------------------------- k0: ALL init
// [0,896) conv-bank frags | [896,960) 1x1 frags | [960,1088) DFT frags |
// 1088 pool coefs | [1089,1729) wp1 frags | [1729,1857) wp2 frags |
// [1857,2369) w_fu frags | [2369,2625) w_out frags | [2625,2657) y1g pad zero
__global__ void k0_all(const float* __restrict__ wt3, const float* __restrict__ wt7,
                       const float* __restrict__ wt15, const float* __restrict__ wt31,
                       const float* __restrict__ w_sp,
                       const float* __restrict__ wp1, const float* __restrict__ wp2,
                       const float* __restrict__ w_fu, const float* __restrict__ w_out,
                       ushort* __restrict__ wfrag, ushort* __restrict__ wfB,
                       ushort* __restrict__ tabf, float4* __restrict__ jc,
                       ushort* __restrict__ wp1f, ushort* __restrict__ wp2f,
                       ushort* __restrict__ wfuf, ushort* __restrict__ woutf,
                       ushort* __restrict__ y1g) {
  int bid = blockIdx.x;
  int tid = threadIdx.x;
  if (bid >= 2625) {                 // zero y1g pad rows (0..15 and 4112..4159)
    int b = bid - 2625;
    unsigned* y1u = (unsigned*)y1g;
    long base = (long)b * Y1ROWS * 64;
#pragma unroll
    for (int it = 0; it < 16; it++) {
      int idx = it * 256 + tid;
      int row = (idx < 1024) ? (idx >> 6) : (4112 + ((idx - 1024) >> 6));
      y1u[base + (long)row * 64 + (idx & 63)] = 0u;
    }
    return;
  }
  if (bid < 896) {
    int e = bid * 256 + tid;
    const float* w; int K, base, eb;
    if (e < 12288)       { w = wt3;  K = 3;  base = 0;   eb = e; }
    else if (e < 40960)  { w = wt7;  K = 7;  base = 48;  eb = e - 12288; }
    else if (e < 102400) { w = wt15; K = 15; base = 160; eb = e - 40960; }
    else                 { w = wt31; K = 31; base = 400; eb = e - 102400; }
    int j = eb / 4096;  int v = eb - j * 4096;
    int ks = v >> 11;   int v2 = v & 2047;
    int tile = v2 >> 9; int wdx = v2 & 511;
    int l = wdx >> 3, i = wdx & 7;
    int o = tile * 16 + (l & 15);
    int c = ks * 32 + 8 * (l >> 4) + i;
    float f = w[(o * 64 + c) * K + j];
    ushort hi = f2bf(f);
    ushort lo = f2bf(f - bf2f(hi));
    int fragp = base + ((j * 2 + ks) * 4 + tile) * 2;
    wfrag[fragp * 512 + wdx] = hi;
    wfrag[(fragp + 1) * 512 + wdx] = lo;
  } else if (bid < 960) {
    int e = (bid - 896) * 256 + tid;
    int frag = e >> 9;
    int wdx = e & 511;
    int l = wdx >> 3, i = wdx & 7;
    int s = frag >> 2, n = frag & 3;
    int c = s * 32 + 8 * (l >> 4) + i;
    int o = n * 16 + (l & 15);
    float f = w_sp[o * 256 + c];
    ushort hi = f2bf(f);
    ushort lo = f2bf(f - bf2f(hi));
    wfB[(frag * 2 + 0) * 512 + wdx] = hi;
    wfB[(frag * 2 + 1) * 512 + wdx] = lo;
  } else if (bid < 1088) {
    int e = (bid - 960) * 256 + tid;
    int fp = e >> 9;
    int wdx = e & 511;
    int l = wdx >> 3, i = wdx & 7;
    int ks = fp >> 3, n = fp & 7;
    int k = ks * 32 + 8 * (l >> 4) + i;
    int fidx = (n & 3) * 16 + (l & 15);
    float v = 0.f;
    if (fidx < 50) {
      int f = fidx + 1;
      int ph = (f * k) & 255;
      float ang = 0.024543692606170259f * (float)ph; // 2*pi/256
      v = (n >= 4) ? sinf(ang) : cosf(ang);
    }
    ushort hi = f2bf(v);
    ushort lo = f2bf(v - bf2f(hi));
    tabf[(fp * 2 + 0) * 512 + wdx] = hi;
    tabf[(fp * 2 + 1) * 512 + wdx] = lo;
  } else if (bid == 1088) {
    if (tid < 128) {
      int l = tid;
      double cc[3] = {0.0, 0.0, 0.0};
      int j0 = -1;
      for (int t = l * 32; t < l * 32 + 32; t++) {
        double src = ((double)t + 0.5) * (31.0 / 4096.0) - 0.5;
        src = src < 0.0 ? 0.0 : (src > 30.0 ? 30.0 : src);
        int i0 = (int)src;
        if (i0 > 30) i0 = 30;
        int i1 = i0 + 1 > 30 ? 30 : i0 + 1;
        double w = src - (double)i0;
        if (j0 < 0) j0 = i0;
        cc[i0 - j0] += 1.0 - w;
        cc[i1 - j0] += w;
      }
      float4 r;
      r.x = __int_as_float(j0);
      r.y = (float)(cc[0] / 32.0);
      r.z = (float)(cc[1] / 32.0);
      r.w = (float)(cc[2] / 32.0);
      jc[l] = r;
    }
  } else if (bid < 1729) {       // wp1 frags: K=1280, N=128, NT=8
    int e = (bid - 1089) * 256 + tid;
    int fp = e >> 9, wdx = e & 511;
    int l = wdx >> 3, i = wdx & 7;
    int ks = fp >> 3, n = fp & 7;
    int k = ks * 32 + 8 * (l >> 4) + i;
    int col = n * 16 + (l & 15);
    float f = wp1[k * 128 + col];
    ushort hi = f2bf(f);
    ushort lo = f2bf(f - bf2f(hi));
    wp1f[(fp * 2 + 0) * 512 + wdx] = hi;
    wp1f[(fp * 2 + 1) * 512 + wdx] = lo;
  } else if (bid < 1857) {       // wp2 frags: K=128, N=256, NT=16
    int e = (bid - 1729) * 256 + tid;
    int fp = e >> 9, wdx = e & 511;
    int l = wdx >> 3, i = wdx & 7;
    int ks = fp >> 4, n = fp & 15;
    int k = ks * 32 + 8 * (l >> 4) + i;
    int col = n * 16 + (l & 15);
    float f = wp2[k * 256 + col];
    ushort hi = f2bf(f);
    ushort lo = f2bf(f - bf2f(hi));
    wp2f[(fp * 2 + 0) * 512 + wdx] = hi;
    wp2f[(fp * 2 + 1) * 512 + wdx] = lo;
  } else if (bid < 2369) {       // w_fu frags: K=512, N=256, NT=16
    int e = (bid - 1857) * 256 + tid;
    int fp = e >> 9, wdx = e & 511;
    int l = wdx >> 3, i = wdx & 7;
    int ks = fp >> 4, n = fp & 15;
    int k = ks * 32 + 8 * (l >> 4) + i;
    int col = n * 16 + (l & 15);
    float f = w_fu[k * 256 + col];
    ushort hi = f2bf(f);
    ushort lo = f2bf(f - bf2f(hi));
    wfuf[(fp * 2 + 0) * 512 + wdx] = hi;
    wfuf[(fp * 2 + 1) * 512 + wdx] = lo;
  } else {                       // w_out frags: K=256, N=256, NT=16
    int e = (bid - 2369) * 256 + tid;
    int fp = e >> 9, wdx = e & 511;
    int l = wdx >> 3, i = wdx & 7;
    int ks = fp >> 4, n = fp & 15;
    int k = ks * 32 + 8 * (l >> 4) + i;
    int col = n * 16 + (l & 15);
    float f = w_out[k * 256 + col];
    ushort hi = f2bf(f);
    ushort lo = f2bf(f - bf2f(hi));
    woutf[(fp * 2 + 0) * 512 + wdx] = hi;
    woutf[(fp * 2 + 1) * 512 + wdx] = lo;
  }
}

// --------------------------------------------- K1: 1x1conv+BN1+ReLU -> y1g (pre-swizzled)
// Scatter the swizzled bf16 hi/lo image into LDS (cheap), then drain to
// global with coalesced 16B/lane stores. y1g contents byte-identical to R3.
__launch_bounds__(512)
__global__ void k1_stage(const float* __restrict__ x, const ushort* __restrict__ wfB,
                         const float* __restrict__ b_sp, const float* __restrict__ g1,
                         const float* __restrict__ be1, const float* __restrict__ m1,
                         const float* __restrict__ v1, ushort* __restrict__ y1g) {
  __shared__ __align__(16) ushort xs[128 * 128];   // 32 KB swizzled tile image
  int tid = threadIdx.x;
  int bid = blockIdx.x;
  int b = bid >> 5;
  int t0 = (bid & 31) * 128;
  int l = tid & 63;
  int wid = tid >> 6;
  int lr = l & 15, lg = l >> 4;
  float sbn1[4], cbn1[4];
#pragma unroll
  for (int n = 0; n < 4; n++) {
    int o = n * 16 + lr;
    float s = g1[o] * rsqrtf(v1[o] + EPS_BN);
    sbn1[n] = s;
    cbn1[n] = (b_sp[o] - m1[o]) * s + be1[o];
  }
  const f32x4 z = {0.f, 0.f, 0.f, 0.f};
  int rowbase = wid * 16;
  const float* __restrict__ xp0 = x + ((long)b * T_LEN + t0 + rowbase + lr) * 256 + 8 * lg;
  f32x4 a1x[4];
#pragma unroll
  for (int n = 0; n < 4; n++) a1x[n] = z;
#pragma unroll 2
  for (int s = 0; s < 8; s++) {
    short8 bh[4], bl[4];
#pragma unroll
    for (int n = 0; n < 4; n++) {
      const ushort* bp = wfB + ((s * 4 + n) * 2) * 512 + l * 8;
      bh[n] = *(const short8*)bp;
      bl[n] = *(const short8*)(bp + 512);
    }
    float4 a0 = *(const float4*)(xp0 + s * 32);
    float4 a1 = *(const float4*)(xp0 + s * 32 + 4);
    float av[8] = {a0.x, a0.y, a0.z, a0.w, a1.x, a1.y, a1.z, a1.w};
    short8 ah, al;
#pragma unroll
    for (int i = 0; i < 8; i++) {
      ushort hi = f2bf(av[i]);
      ah[i] = (short)hi;
      al[i] = (short)f2bf(av[i] - bf2f(hi));
    }
#pragma unroll
    for (int n = 0; n < 4; n++) {
      a1x[n] = __builtin_amdgcn_mfma_f32_16x16x32_bf16(ah, bh[n], a1x[n], 0, 0, 0);
      a1x[n] = __builtin_amdgcn_mfma_f32_16x16x32_bf16(al, bh[n], a1x[n], 0, 0, 0);
      a1x[n] = __builtin_amdgcn_mfma_f32_16x16x32_bf16(ah, bl[n], a1x[n], 0, 0, 0);
    }
  }
#pragma unroll
  for (int r = 0; r < 4; r++) {
    int row = rowbase + lg * 4 + r;        // local row 0..127, t = t0 + row
    int sw = (row + 15) & 15;              // == (t+15)&15 since t0 % 16 == 0
#pragma unroll
    for (int n = 0; n < 4; n++) {
      float v = fmaxf(fmaf(a1x[n][r], sbn1[n], cbn1[n]), 0.f);
      ushort hi = f2bf(v);
      ushort lo = f2bf(v - bf2f(hi));
      int c = n * 16 + lr;
      int g = c >> 3;
      xs[row * 128 + (((g ^ sw) << 3) | (c & 7))] = hi;
      xs[row * 128 + ((((g + 8) ^ sw) << 3) | (c & 7))] = lo;
    }
  }
  __syncthreads();
  // drain LDS -> y1g, coalesced: 2048 uint4 total, 512 threads x 4
  long gb = ((long)b * Y1ROWS + 16 + t0) * 128;
  const uint4* __restrict__ src = (const uint4*)xs;
  uint4* __restrict__ dst = (uint4*)(y1g + gb);
  int base = tid;
#pragma unroll
  for (int i = 0; i < 4; i++)
    dst[base + i * 512] = src[base + i * 512];
}

// --------------------------------------------- K2: multi-scale conv (LDS-staged y1)
#define XR2 160   // 128 t-tile + 30 halo rows (+2 load rounding)

__device__ __forceinline__ void conv_accum(
    const ushort* __restrict__ xs, const ushort* __restrict__ wfb,
    int jlo, int jhi, int SH, int h, int l,
    f32x4* __restrict__ acc0, f32x4* __restrict__ acc1) {
  int lr = l & 15, lg = l >> 4;
  int U = (jhi - jlo) * 2;   // u enumerates (j,ks) steps
  short8 c0h, c0l, c1h, c1l;
  {
    const ushort* ap = wfb + (((jlo * 2 + 0) * 4 + h * 2) * 2) * 512 + l * 8;
    c0h = *(const short8*)(ap);
    c0l = *(const short8*)(ap + 512);
    c1h = *(const short8*)(ap + 1024);
    c1l = *(const short8*)(ap + 1536);
  }
#pragma unroll 1
  for (int u = 0; u < U; u++) {
    int un = (u + 1 < U) ? u + 1 : u;
    int jn = jlo + (un >> 1), kn = un & 1;
    const ushort* apn = wfb + (((jn * 2 + kn) * 4 + h * 2) * 2) * 512 + l * 8;
    short8 n0h = *(const short8*)(apn);
    short8 n0l = *(const short8*)(apn + 512);
    short8 n1h = *(const short8*)(apn + 1024);
    short8 n1l = *(const short8*)(apn + 1536);

    int j = jlo + (u >> 1), ks = u & 1;
    int rs = j + SH;
    int gb = ks * 4 + lg;
#pragma unroll
    for (int tt = 0; tt < 8; tt++) {
      int row = tt * 16 + lr + rs;
      int sw = (row & 15) << 3;
      short8 bhi = *(const short8*)&xs[row * 128 + ((gb << 3) ^ sw)];
      short8 blo = *(const short8*)&xs[row * 128 + (((gb + 8) << 3) ^ sw)];
      acc0[tt] = __builtin_amdgcn_mfma_f32_16x16x32_bf16(c0h, bhi, acc0[tt], 0, 0, 0);
      acc0[tt] = __builtin_amdgcn_mfma_f32_16x16x32_bf16(c0h, blo, acc0[tt], 0, 0, 0);
      acc0[tt] = __builtin_amdgcn_mfma_f32_16x16x32_bf16(c0l, bhi, acc0[tt], 0, 0, 0);
      acc1[tt] = __builtin_amdgcn_mfma_f32_16x16x32_bf16(c1h, bhi, acc1[tt], 0, 0, 0);
      acc1[tt] = __builtin_amdgcn_mfma_f32_16x16x32_bf16(c1h, blo, acc1[tt], 0, 0, 0);
      acc1[tt] = __builtin_amdgcn_mfma_f32_16x16x32_bf16(c1l, bhi, acc1[tt], 0, 0, 0);
    }
    c0h = n0h; c0l = n0l; c1h = n1h; c1l = n1l;
  }
}

__device__ __forceinline__ void conv_epilogue(
    const f32x4* __restrict__ acc0, const f32x4* __restrict__ acc1,
    const float* __restrict__ bk, const float* __restrict__ g2,
    const float* __restrict__ be2, const float* __restrict__ m2,
    const float* __restrict__ v2,
    unsigned* __restrict__ y2p, float* __restrict__ pv,
    int b, int t0, int l, int h, int chb) {
  int lr = l & 15, lg = l >> 4;
#pragma unroll
  for (int ti = 0; ti < 2; ti++) {
#pragma unroll
    for (int r = 0; r < 4; r++) {
      int och = chb + h * 32 + ti * 16 + 4 * lg + r;
      float bias = bk[och - chb];
      float s = g2[och] * rsqrtf(v2[och] + EPS_BN);
      float sh = be2[och] - m2[och] * s;
      long idx = ((long)(b * 256 + och)) * T_LEN + t0 + lr;
      float pl[4] = {0.f, 0.f, 0.f, 0.f};
#pragma unroll
      for (int tt = 0; tt < 8; tt++) {
        float a = ti ? acc1[tt][r] : acc0[tt][r];
        float v = fmaf(fmaxf(a + bias, 0.f), s, sh);
        ushort hi = f2bf(v);
        ushort lo = f2bf(v - bf2f(hi));
        y2p[idx + tt * 16] = (unsigned)hi | ((unsigned)lo << 16);
        pl[tt >> 1] += v;
      }
#pragma unroll
      for (int j = 0; j < 4; j++) {
#pragma unroll
        for (int m = 1; m < 16; m <<= 1) pl[j] += __shfl_xor(pl[j], m);
      }
      if (lr == 0) {
#pragma unroll
        for (int j = 0; j < 4; j++)
          pv[((long)(b * 128 + (t0 >> 5) + j)) * 512 + och] = pl[j] * (1.f / 32.f);
      }
    }
  }
}

__launch_bounds__(512, 4)
__global__ void k2_convbank(const ushort* __restrict__ y1g,
    const ushort* __restrict__ wfrag,
    const float* __restrict__ bt3, const float* __restrict__ bt7,
    const float* __restrict__ bt15, const float* __restrict__ bt31,
    const float* __restrict__ g2, const float* __restrict__ be2,
    const float* __restrict__ m2, const float* __restrict__ v2,
    unsigned* __restrict__ y2p, float* __restrict__ pv) {
  __shared__ __align__(16) ushort xs[XR2 * 128];   // staged tile; reused as f32x4 red[]
  int tid = threadIdx.x;
  int bid = blockIdx.x;
  int b = bid >> 5;
  int t0 = (bid & 31) * 128;
  int l = tid & 63;
  int wid = __builtin_amdgcn_readfirstlane(tid >> 6);

  // ---- staging: 160 rows (t0-15 .. t0+144) from pre-swizzled y1g.
  // LDS row r <-> padded row t0+1+r; 1 KB per instr, 5 per wave.
  {
    long gb = ((long)b * Y1ROWS + t0 + 1) * 128;
    const ushort* gpw = y1g + gb + (long)(wid * 20) * 128;
    int lo = ((l >> 4) * 128 + (l & 15) * 8);
    uint4 v[5];
#pragma unroll
    for (int i = 0; i < 5; i++)
      v[i] = *(const uint4*)(gpw + i * 512 + lo);
#pragma unroll
    for (int i = 0; i < 5; i++)
      *(uint4*)&xs[(wid * 5 + i) * 512 + l * 8] = v[i];
  }
  __syncthreads();

  // ---- conv phase
  int beta, h, jlo, jhi, role, slot;   // role: 0 direct, 1 flush, 2 add
  switch (wid) {
    case 0:  beta = 3; h = 0; jlo = 0;  jhi = 16; role = 2; slot = 0; break;
    case 1:  beta = 3; h = 0; jlo = 16; jhi = 31; role = 1; slot = 0; break;
    case 2:  beta = 3; h = 1; jlo = 0;  jhi = 16; role = 2; slot = 1; break;
    case 3:  beta = 3; h = 1; jlo = 16; jhi = 31; role = 1; slot = 1; break;
    case 4:  beta = 2; h = 0; jlo = 0;  jhi = 15; role = 0; slot = 0; break;
    case 5:  beta = 2; h = 1; jlo = 0;  jhi = 15; role = 0; slot = 0; break;
    case 6:  beta = 1; h = 0; jlo = 0;  jhi = 7;  role = 0; slot = 0; break;
    default: beta = 1; h = 1; jlo = 0;  jhi = 7;  role = 0; slot = 0; break;
  }
  const int FB[4]  = {0, 48, 160, 400};
  const int SHs[4] = {14, 12, 8, 0};
  const int CHB[4] = {0, 64, 128, 192};
  const float* bk = (beta == 0) ? bt3 : (beta == 1) ? bt7 : (beta == 2) ? bt15 : bt31;

  f32x4 acc0[8], acc1[8];
  const f32x4 z = {0.f, 0.f, 0.f, 0.f};
#pragma unroll
  for (int tt = 0; tt < 8; tt++) { acc0[tt] = z; acc1[tt] = z; }

  conv_accum(xs, wfrag + FB[beta] * 512, jlo, jhi, SHs[beta], h, l, acc0, acc1);
  if (role == 0) {
    conv_epilogue(acc0, acc1, bk, g2, be2, m2, v2, y2p, pv, b, t0, l, h, CHB[beta]);
    if (wid >= 6) {   // second pass: K=3 branch on same half
#pragma unroll
      for (int tt = 0; tt < 8; tt++) { acc0[tt] = z; acc1[tt] = z; }
      conv_accum(xs, wfrag, 0, 3, 14, h, l, acc0, acc1);
      conv_epilogue(acc0, acc1, bt3, g2, be2, m2, v2, y2p, pv, b, t0, l, h, 0);
    }
  }
  __syncthreads();                       // xs reads complete everywhere
  f32x4* red = (f32x4*)xs;
  if (role == 1) {
    f32x4* rp = red + (slot * 64 + l) * 16;
#pragma unroll
    for (int tt = 0; tt < 8; tt++) {
      rp[(tt * 2 + 0) ^ (l & 15)] = acc0[tt];
      rp[(tt * 2 + 1) ^ (l & 15)] = acc1[tt];
    }
  }
  __syncthreads();
  if (role == 2) {
    const f32x4* rp = red + (slot * 64 + l) * 16;
#pragma unroll
    for (int tt = 0; tt < 8; tt++) {
      acc0[tt] += rp[(tt * 2 + 0) ^ (l & 15)];
      acc1[tt] += rp[(tt * 2 + 1) ^ (l & 15)];
    }
    conv_epilogue(acc0, acc1, bt31, g2, be2, m2, v2, y2p, pv, b, t0, l, h, 192);
  }
}

// --------------------------------------------- K3: windowed DFT powers via MFMA
__launch_bounds__(512)
__global__ void k3_spectral(const unsigned* __restrict__ y2p,
                            const ushort* __restrict__ tabf, float* __restrict__ h0) {
  int tid = threadIdx.x;
  int l = tid & 63;
  int wid = tid >> 6;            // wave owns ch 32*wid .. +31 (2 M-tiles)
  int bid = (int)(blockIdx.x % 8u) * 124 + (int)(blockIdx.x / 8u);
  int win = bid % NWIN;
  int b = bid / NWIN;
  int t0 = win * 128;
  int lr = l & 15, lg = l >> 4;
  f32x4 acc[2][8];
  const f32x4 z = {0.f, 0.f, 0.f, 0.f};
#pragma unroll
  for (int mt = 0; mt < 2; mt++)
#pragma unroll
    for (int n = 0; n < 8; n++) acc[mt][n] = z;
  long abase = ((long)(b * 256 + wid * 32 + lr)) * T_LEN + t0 + 8 * lg;
  const unsigned* __restrict__ xp = y2p + abase;
  uint4 cA0[2], cA1[2];
#pragma unroll
  for (int mt = 0; mt < 2; mt++) {
    const uint4* p = (const uint4*)(xp + (long)mt * 16 * T_LEN);
    cA0[mt] = p[0];
    cA1[mt] = p[1];
  }
#pragma unroll 1
  for (int ks = 0; ks < 8; ks++) {
    uint4 nA0[2], nA1[2];
    if (ks < 7) {
#pragma unroll
      for (int mt = 0; mt < 2; mt++) {
        const uint4* p = (const uint4*)(xp + (long)mt * 16 * T_LEN + (ks + 1) * 32);
        nA0[mt] = p[0];
        nA1[mt] = p[1];
      }
    } else {
#pragma unroll
      for (int mt = 0; mt < 2; mt++) { nA0[mt] = cA0[mt]; nA1[mt] = cA1[mt]; }
    }
    short8 ah[2], al[2];
#pragma unroll
    for (int mt = 0; mt < 2; mt++) {
      unsigned vv[8] = {cA0[mt].x, cA0[mt].y, cA0[mt].z, cA0[mt].w,
                        cA1[mt].x, cA1[mt].y, cA1[mt].z, cA1[mt].w};
#pragma unroll
      for (int i = 0; i < 8; i++) {
        ah[mt][i] = (short)(vv[i] & 0xffffu);
        al[mt][i] = (short)(vv[i] >> 16);
      }
    }
#pragma unroll
    for (int n = 0; n < 8; n++) {
      const ushort* bp = tabf + ((ks * 8 + n) * 2) * 512 + l * 8;
      short8 bh = *(const short8*)bp;
      short8 bl = *(const short8*)(bp + 512);
#pragma unroll
      for (int mt = 0; mt < 2; mt++) {
        acc[mt][n] = __builtin_amdgcn_mfma_f32_16x16x32_bf16(ah[mt], bh, acc[mt][n], 0, 0, 0);
        acc[mt][n] = __builtin_amdgcn_mfma_f32_16x16x32_bf16(al[mt], bh, acc[mt][n], 0, 0, 0);
        acc[mt][n] = __builtin_amdgcn_mfma_f32_16x16x32_bf16(ah[mt], bl, acc[mt][n], 0, 0, 0);
      }
    }
#pragma unroll
    for (int mt = 0; mt < 2; mt++) { cA0[mt] = nA0[mt]; cA1[mt] = nA1[mt]; }
  }
  float wt[4][5];
#pragma unroll
  for (int n = 0; n < 4; n++) {
    int f = n * 16 + lr;
    wt[n][0] = (f <= 3)            ? 0.25f        : 0.f;
    wt[n][1] = (f >= 3 && f <= 7)  ? 0.2f         : 0.f;
    wt[n][2] = (f >= 7 && f <= 12) ? (1.f / 6.f)  : 0.f;
    wt[n][3] = (f >= 12 && f <= 29)? (1.f / 18.f) : 0.f;
    wt[n][4] = (f >= 29 && f <= 49)? (1.f / 21.f) : 0.f;
  }
  long hb = ((long)(b * NWIN + win)) * 1280;
#pragma unroll
  for (int mt = 0; mt < 2; mt++) {
#pragma unroll
    for (int r = 0; r < 4; r++) {
      float p0, p1, p2, p3;
      { float re = acc[mt][0][r], im = acc[mt][4][r]; p0 = re * re + im * im; }
      { float re = acc[mt][1][r], im = acc[mt][5][r]; p1 = re * re + im * im; }
      { float re = acc[mt][2][r], im = acc[mt][6][r]; p2 = re * re + im * im; }
      { float re = acc[mt][3][r], im = acc[mt][7][r]; p3 = re * re + im * im; }
      float s0 = p0 * wt[0][0] + p1 * wt[1][0] + p2 * wt[2][0] + p3 * wt[3][0];
      float s1 = p0 * wt[0][1] + p1 * wt[1][1] + p2 * wt[2][1] + p3 * wt[3][1];
      float s2 = p0 * wt[0][2] + p1 * wt[1][2] + p2 * wt[2][2] + p3 * wt[3][2];
      float s3 = p0 * wt[0][3] + p1 * wt[1][3] + p2 * wt[2][3] + p3 * wt[3][3];
      float s4 = p0 * wt[0][4] + p1 * wt[1][4] + p2 * wt[2][4] + p3 * wt[3][4];
#pragma unroll
      for (int m = 1; m < 16; m <<= 1) {
        s0 += __shfl_xor(s0, m);
        s1 += __shfl_xor(s1, m);
        s2 += __shfl_xor(s2, m);
        s3 += __shfl_xor(s3, m);
        s4 += __shfl_xor(s4, m);
      }
      if (lr < 5) {
        float out = lr == 0 ? s0 : lr == 1 ? s1 : lr == 2 ? s2 : lr == 3 ? s3 : s4;
        int ch = wid * 32 + mt * 16 + lg * 4 + r;
        h0[hb + lr * 256 + ch] = out;
      }
    }
  }
}

// --------------------------------------------- K4: spectral MLP via MFMA
// Block = 16 rows, 4 waves = n-quarters. Layer1 K=1280, layer2 K=128.
__launch_bounds__(256)
__global__ void k4_mlp(const float* __restrict__ h0, const ushort* __restrict__ wp1f,
                       const float* __restrict__ bp1, const ushort* __restrict__ wp2f,
                       const float* __restrict__ bp2, float* __restrict__ hs) {
  __shared__ ushort t1h[16][136];
  __shared__ ushort t1l[16][136];
  int tid = threadIdx.x;
  int l = tid & 63, wid = tid >> 6;
  int lr = l & 15, lg = l >> 4;
  int r0 = blockIdx.x * 16;
  const float* __restrict__ ap0 = h0 + (long)(r0 + lr) * 1280 + 8 * lg;
  const f32x4 z = {0.f, 0.f, 0.f, 0.f};
  f32x4 acc[2];
  acc[0] = z; acc[1] = z;
#pragma unroll 2
  for (int ks = 0; ks < 40; ks++) {
    float4 a0 = *(const float4*)(ap0 + ks * 32);
    float4 a1 = *(const float4*)(ap0 + ks * 32 + 4);
    float av[8] = {a0.x, a0.y, a0.z, a0.w, a1.x, a1.y, a1.z, a1.w};
    short8 ah, al;
#pragma unroll
    for (int i = 0; i < 8; i++) {
      ushort hi = f2bf(av[i]);
      ah[i] = (short)hi;
      al[i] = (short)f2bf(av[i] - bf2f(hi));
    }
#pragma unroll
    for (int nt = 0; nt < 2; nt++) {
      const ushort* bp = wp1f + ((ks * 8 + wid * 2 + nt) * 2) * 512 + l * 8;
      short8 bh = *(const short8*)bp;
      short8 bl = *(const short8*)(bp + 512);
      acc[nt] = __builtin_amdgcn_mfma_f32_16x16x32_bf16(ah, bh, acc[nt], 0, 0, 0);
      acc[nt] = __builtin_amdgcn_mfma_f32_16x16x32_bf16(al, bh, acc[nt], 0, 0, 0);
      acc[nt] = __builtin_amdgcn_mfma_f32_16x16x32_bf16(ah, bl, acc[nt], 0, 0, 0);
    }
  }
#pragma unroll
  for (int nt = 0; nt < 2; nt++) {
    int col = (wid * 2 + nt) * 16 + lr;
    float bb = bp1[col];
#pragma unroll
    for (int r = 0; r < 4; r++) {
      int row = lg * 4 + r;
      float v = fmaxf(acc[nt][r] + bb, 0.f);
      ushort hi = f2bf(v);
      ushort lo = f2bf(v - bf2f(hi));
      t1h[row][col] = hi;
      t1l[row][col] = lo;
    }
  }
  __syncthreads();
  f32x4 a2[4];
#pragma unroll
  for (int nt = 0; nt < 4; nt++) a2[nt] = z;
#pragma unroll
  for (int ks = 0; ks < 4; ks++) {
    short8 ah = *(const short8*)&t1h[lr][ks * 32 + 8 * lg];
    short8 al = *(const short8*)&t1l[lr][ks * 32 + 8 * lg];
#pragma unroll
    for (int nt = 0; nt < 4; nt++) {
      const ushort* bp = wp2f + ((ks * 16 + wid * 4 + nt) * 2) * 512 + l * 8;
      short8 bh = *(const short8*)bp;
      short8 bl = *(const short8*)(bp + 512);
      a2[nt] = __builtin_amdgcn_mfma_f32_16x16x32_bf16(ah, bh, a2[nt], 0, 0, 0);
      a2[nt] = __builtin_amdgcn_mfma_f32_16x16x32_bf16(al, bh, a2[nt], 0, 0, 0);
      a2[nt] = __builtin_amdgcn_mfma_f32_16x16x32_bf16(ah, bl, a2[nt], 0, 0, 0);
    }
  }
#pragma unroll
  for (int nt = 0; nt < 4; nt++) {
    int col = (wid * 4 + nt) * 16 + lr;
    float bb = bp2[col];
#pragma unroll
    for (int r = 0; r < 4; r++) {
      long row = r0 + lg * 4 + r;
      hs[row * 256 + col] = a2[nt][r] + bb;
    }
  }
}

// --------------------------------------------- K5a: spec interp (3-coef) -> pv
__launch_bounds__(256)
__global__ void k5a_spec(const float* __restrict__ hs, const float4* __restrict__ jc,
                         float* __restrict__ pv) {
  int o = threadIdx.x;
  int l = blockIdx.x & 127, b = blockIdx.x >> 7;
  float4 c = jc[l];
  int j0 = __float_as_int(c.x);
  const float* __restrict__ hb = hs + (long)b * NWIN * 256;
  int i0 = j0 > 30 ? 30 : j0;
  int i1 = j0 + 1 > 30 ? 30 : j0 + 1;
  int i2 = j0 + 2 > 30 ? 30 : j0 + 2;
  float v = c.y * hb[i0 * 256 + o] + c.z * hb[i1 * 256 + o] + c.w * hb[i2 * 256 + o];
  pv[((long)(b * 128 + l)) * 512 + 256 + o] = v;
}

// --------------------------------------------- K5b: fused proj + pos + out proj via MFMA
// Block = 32 rows (2 M-tiles), 4 waves = (m-tile, n-half). K=512 then K=256.
__launch_bounds__(256)
__global__ void k5b_out(const float* __restrict__ pv, const ushort* __restrict__ wfuf,
                        const float* __restrict__ b_fu, const float* __restrict__ pos,
                        const ushort* __restrict__ woutf, const float* __restrict__ b_out,
                        float* __restrict__ out) {
  __shared__ ushort gh[32][264];
  __shared__ ushort gl[32][264];
  int tid = threadIdx.x;
  int l = tid & 63, wid = tid >> 6;
  int lr = l & 15, lg = l >> 4;
  int mt = wid & 1, nh = wid >> 1;
  int r0 = blockIdx.x * 32;
  int lbase = r0 & 127;
  const float* __restrict__ ap0 = pv + (long)(r0 + mt * 16 + lr) * 512 + 8 * lg;
  const f32x4 z = {0.f, 0.f, 0.f, 0.f};
  f32x4 acc[8];
#pragma unroll
  for (int nt = 0; nt < 8; nt++) acc[nt] = z;
#pragma unroll 1
  for (int ks = 0; ks < 16; ks++) {
    float4 a0 = *(const float4*)(ap0 + ks * 32);
    float4 a1 = *(const float4*)(ap0 + ks * 32 + 4);
    float av[8] = {a0.x, a0.y, a0.z, a0.w, a1.x, a1.y, a1.z, a1.w};
    short8 ah, al;
#pragma unroll
    for (int i = 0; i < 8; i++) {
      ushort hi = f2bf(av[i]);
      ah[i] = (short)hi;
      al[i] = (short)f2bf(av[i] - bf2f(hi));
    }
#pragma unroll
    for (int nt = 0; nt < 8; nt++) {
      const ushort* bp = wfuf + ((ks * 16 + nh * 8 + nt) * 2) * 512 + l * 8;
      short8 bh = *(const short8*)bp;
      short8 bl = *(const short8*)(bp + 512);
      acc[nt] = __builtin_amdgcn_mfma_f32_16x16x32_bf16(ah, bh, acc[nt], 0, 0, 0);
      acc[nt] = __builtin_amdgcn_mfma_f32_16x16x32_bf16(al, bh, acc[nt], 0, 0, 0);
      acc[nt] = __builtin_amdgcn_mfma_f32_16x16x32_bf16(ah, bl, acc[nt], 0, 0, 0);
    }
  }
#pragma unroll
  for (int nt = 0; nt < 8; nt++) {
    int col = (nh * 8 + nt) * 16 + lr;
    float bb = b_fu[col];
#pragma unroll
    for (int r = 0; r < 4; r++) {
      int row = mt * 16 + lg * 4 + r;
      float v = acc[nt][r] + bb + pos[(lbase + row) * 256 + col];
      ushort hi = f2bf(v);
      ushort lo = f2bf(v - bf2f(hi));
      gh[row][col] = hi;
      gl[row][col] = lo;
    }
  }
  __syncthreads();
  f32x4 a2[8];
#pragma unroll
  for (int nt = 0; nt < 8; nt++) a2[nt] = z;
#pragma unroll 1
  for (int ks = 0; ks < 8; ks++) {
    short8 ah = *(const short8*)&gh[mt * 16 + lr][ks * 32 + 8 * lg];
    short8 al = *(const short8*)&gl[mt * 16 + lr][ks * 32 + 8 * lg];
#pragma unroll
    for (int nt = 0; nt < 8; nt++) {
      const ushort* bp = woutf + ((ks * 16 + nh * 8 + nt) * 2) * 512 + l * 8;
      short8 bh = *(const short8*)bp;
      short8 bl = *(const short8*)(bp + 512);
      a2[nt] = __builtin_amdgcn_mfma_f32_16x16x32_bf16(ah, bh, a2[nt], 0, 0, 0);
      a2[nt] = __builtin_amdgcn_mfma_f32_16x16x32_bf16(al, bh, a2[nt], 0, 0, 0);
      a2[nt] = __builtin_amdgcn_mfma_f32_16x16x32_bf16(ah, bl, a2[nt], 0, 0, 0);
    }
  }
#pragma unroll
  for (int nt = 0; nt < 8; nt++) {
    int col = (nh * 8 + nt) * 16 + lr;
    float bb = b_out[col];
#pragma unroll
    for (int r = 0; r < 4; r++) {
      long row = r0 + mt * 16 + lg * 4 + r;
      out[row * 256 + col] = a2[nt][r] + bb;
    }
  }
}

// ---------------------------------------------------------------- launcher
extern "C" void kernel_launch(void* const* d_in, const int* in_sizes, int n_in,
                              void* d_out, int out_size, void* d_ws, size_t ws_size,
                              hipStream_t stream) {
  const float* x    = (const float*)d_in[0];
  const float* w_sp = (const float*)d_in[1];
  const float* b_sp = (const float*)d_in[2];
  const float* g1   = (const float*)d_in[3];
  const float* be1  = (const float*)d_in[4];
  const float* m1   = (const float*)d_in[5];
  const float* v1   = (const float*)d_in[6];
  const float* wt3  = (const float*)d_in[7];
  const float* bt3  = (const float*)d_in[8];
  const float* wt7  = (const float*)d_in[9];
  const float* bt7  = (const float*)d_in[10];
  const float* wt15 = (const float*)d_in[11];
  const float* bt15 = (const float*)d_in[12];
  const float* wt31 = (const float*)d_in[13];
  const float* bt31 = (const float*)d_in[14];
  const float* g2   = (const float*)d_in[15];
  const float* be2  = (const float*)d_in[16];
  const float* m2   = (const float*)d_in[17];
  const float* v2   = (const float*)d_in[18];
  const float* wp1  = (const float*)d_in[19];
  const float* bp1  = (const float*)d_in[20];
  const float* wp2  = (const float*)d_in[21];
  const float* bp2  = (const float*)d_in[22];
  const float* w_fu = (const float*)d_in[23];
  const float* b_fu = (const float*)d_in[24];
  const float* pos  = (const float*)d_in[25];
  const float* w_out= (const float*)d_in[26];
  const float* b_out= (const float*)d_in[27];

  unsigned* y2p = (unsigned*)d_ws;         // 33,554,432 uint (bf16 hi|lo packed)
  float* h0  = (float*)(y2p + 33554432);   //  1,269,760 f32
  float* hs  = h0 + 1269760;               //    253,952
  float* pv  = hs + 253952;                //  2,097,152
  float4* jc = (float4*)(pv + 2097152);    //        128 float4
  ushort* wfrag = (ushort*)(jc + 128);     //    458,752 ushort (conv-bank frags)
  ushort* wfB   = wfrag + 458752;          //     32,768 ushort (1x1 frags)
  ushort* tabf  = wfB + 32768;             //     65,536 ushort (DFT table frags)
  ushort* wp1f  = tabf + 65536;            //    327,680 ushort (wp1 frags)
  ushort* wp2f  = wp1f + 327680;           //     65,536 ushort (wp2 frags)
  ushort* wfuf  = wp2f + 65536;            //    262,144 ushort (w_fu frags)
  ushort* woutf = wfuf + 262144;           //    131,072 ushort (w_out frags)
  ushort* y1g   = woutf + 131072;          // 17,039,360 ushort (padded swizzled y1)

  k0_all<<<2657, 256, 0, stream>>>(wt3, wt7, wt15, wt31, w_sp, wp1, wp2, w_fu, w_out,
                                   wfrag, wfB, tabf, jc, wp1f, wp2f, wfuf, woutf, y1g);
  k1_stage<<<1024, 512, 0, stream>>>(x, wfB, b_sp, g1, be1, m1, v1, y1g);
  k2_convbank<<<1024, 512, 0, stream>>>(y1g, wfrag, bt3, bt7, bt15, bt31,
                                        g2, be2, m2, v2, y2p, pv);
  k3_spectral<<<32 * NWIN, 512, 0, stream>>>(y2p, tabf, h0);
  k4_mlp<<<62, 256, 0, stream>>>(h0, wp1f, bp1, wp2f, bp2, hs);
  k5a_spec<<<32 * 128, 256, 0, stream>>>(hs, jc, pv);
  k5b_out<<<128, 256, 0, stream>>>(pv, wfuf, b_fu, pos, woutf, b_out,
                                   (float*)d_out);
}

// Round 5
// 391.649 us; speedup vs baseline: 1.0126x; 1.0059x over previous
//
#include <hip/hip_runtime.h>
#include <hip/hip_bf16.h>

#define T_LEN 4096
#define NWIN 31
#define EPS_BN 1e-5f

typedef __attribute__((ext_vector_type(8))) short short8;
typedef __attribute__((ext_vector_type(4))) float f32x4;

__device__ __forceinline__ ushort f2bf(float x) {   // round-to-nearest-even bf16
  unsigned u = __float_as_uint(x);
  return (ushort)((u + 0x7FFFu + ((u >> 16) & 1u)) >> 16);
}
__device__ __forceinline__ float bf2f(ushort h) {
  return __uint_as_float((unsigned)h << 16);
}

// y1g padded rows: 16 front pad + 4096 data + 48 back pad = 4160 rows of
// 128 ushorts (64ch hi/lo, swizzled by (t+15)&15). Pads zeroed in k0.
#define Y1ROWS 4160

// ---------------------------------------------------------------- k0: ALL init
__global__ void k0_all(const float* __restrict__ wt3, const float* __restrict__ wt7,
                       const float* __restrict__ wt15, const float* __restrict__ wt31,
                       const float* __restrict__ w_sp,
                       const float* __restrict__ wp1, const float* __restrict__ wp2,
                       const float* __restrict__ w_fu, const float* __restrict__ w_out,
                       ushort* __restrict__ wfrag, ushort* __restrict__ wfB,
                       ushort* __restrict__ tabf, float4* __restrict__ jc,
                       ushort* __restrict__ wp1f, ushort* __restrict__ wp2f,
                       ushort* __restrict__ wfuf, ushort* __restrict__ woutf,
                       ushort* __restrict__ y1g) {
  int bid = blockIdx.x;
  int tid = threadIdx.x;
  if (bid >= 2625) {                 // zero y1g pad rows (0..15 and 4112..4159)
    int b = bid - 2625;
    unsigned* y1u = (unsigned*)y1g;
    long base = (long)b * Y1ROWS * 64;
#pragma unroll
    for (int it = 0; it < 16; it++) {
      int idx = it * 256 + tid;
      int row = (idx < 1024) ? (idx >> 6) : (4112 + ((idx - 1024) >> 6));
      y1u[base + (long)row * 64 + (idx & 63)] = 0u;
    }
    return;
  }
  if (bid < 896) {
    int e = bid * 256 + tid;
    const float* w; int K, base, eb;
    if (e < 12288)       { w = wt3;  K = 3;  base = 0;   eb = e; }
    else if (e < 40960)  { w = wt7;  K = 7;  base = 48;  eb = e - 12288; }
    else if (e < 102400) { w = wt15; K = 15; base = 160; eb = e - 40960; }
    else                 { w = wt31; K = 31; base = 400; eb = e - 102400; }
    int j = eb / 4096;  int v = eb - j * 4096;
    int ks = v >> 11;   int v2 = v & 2047;
    int tile = v2 >> 9; int wdx = v2 & 511;
    int l = wdx >> 3, i = wdx & 7;
    int o = tile * 16 + (l & 15);
    int c = ks * 32 + 8 * (l >> 4) + i;
    float f = w[(o * 64 + c) * K + j];
    ushort hi = f2bf(f);
    ushort lo = f2bf(f - bf2f(hi));
    int fragp = base + ((j * 2 + ks) * 4 + tile) * 2;
    wfrag[fragp * 512 + wdx] = hi;
    wfrag[(fragp + 1) * 512 + wdx] = lo;
  } else if (bid < 960) {
    int e = (bid - 896) * 256 + tid;
    int frag = e >> 9;
    int wdx = e & 511;
    int l = wdx >> 3, i = wdx & 7;
    int s = frag >> 2, n = frag & 3;
    int c = s * 32 + 8 * (l >> 4) + i;
    int o = n * 16 + (l & 15);
    float f = w_sp[o * 256 + c];
    ushort hi = f2bf(f);
    ushort lo = f2bf(f - bf2f(hi));
    wfB[(frag * 2 + 0) * 512 + wdx] = hi;
    wfB[(frag * 2 + 1) * 512 + wdx] = lo;
  } else if (bid < 1088) {
    int e = (bid - 960) * 256 + tid;
    int fp = e >> 9;
    int wdx = e & 511;
    int l = wdx >> 3, i = wdx & 7;
    int ks = fp >> 3, n = fp & 7;
    int k = ks * 32 + 8 * (l >> 4) + i;
    int fidx = (n & 3) * 16 + (l & 15);
    float v = 0.f;
    if (fidx < 50) {
      int f = fidx + 1;
      int ph = (f * k) & 255;
      float ang = 0.024543692606170259f * (float)ph; // 2*pi/256
      v = (n >= 4) ? sinf(ang) : cosf(ang);
    }
    ushort hi = f2bf(v);
    ushort lo = f2bf(v - bf2f(hi));
    tabf[(fp * 2 + 0) * 512 + wdx] = hi;
    tabf[(fp * 2 + 1) * 512 + wdx] = lo;
  } else if (bid == 1088) {
    if (tid < 128) {
      int l = tid;
      double cc[3] = {0.0, 0.0, 0.0};
      int j0 = -1;
      for (int t = l * 32; t < l * 32 + 32; t++) {
        double src = ((double)t + 0.5) * (31.0 / 4096.0) - 0.5;
        src = src < 0.0 ? 0.0 : (src > 30.0 ? 30.0 : src);
        int i0 = (int)src;
        if (i0 > 30) i0 = 30;
        int i1 = i0 + 1 > 30 ? 30 : i0 + 1;
        double w = src - (double)i0;
        if (j0 < 0) j0 = i0;
        cc[i0 - j0] += 1.0 - w;
        cc[i1 - j0] += w;
      }
      float4 r;
      r.x = __int_as_float(j0);
      r.y = (float)(cc[0] / 32.0);
      r.z = (float)(cc[1] / 32.0);
      r.w = (float)(cc[2] / 32.0);
      jc[l] = r;
    }
  } else if (bid < 1729) {       // wp1 frags: K=1280, N=128, NT=8
    int e = (bid - 1089) * 256 + tid;
    int fp = e >> 9, wdx = e & 511;
    int l = wdx >> 3, i = wdx & 7;
    int ks = fp >> 3, n = fp & 7;
    int k = ks * 32 + 8 * (l >> 4) + i;
    int col = n * 16 + (l & 15);
    float f = wp1[k * 128 + col];
    ushort hi = f2bf(f);
    ushort lo = f2bf(f - bf2f(hi));
    wp1f[(fp * 2 + 0) * 512 + wdx] = hi;
    wp1f[(fp * 2 + 1) * 512 + wdx] = lo;
  } else if (bid < 1857) {       // wp2 frags: K=128, N=256, NT=16
    int e = (bid - 1729) * 256 + tid;
    int fp = e >> 9, wdx = e & 511;
    int l = wdx >> 3, i = wdx & 7;
    int ks = fp >> 4, n = fp & 15;
    int k = ks * 32 + 8 * (l >> 4) + i;
    int col = n * 16 + (l & 15);
    float f = wp2[k * 256 + col];
    ushort hi = f2bf(f);
    ushort lo = f2bf(f - bf2f(hi));
    wp2f[(fp * 2 + 0) * 512 + wdx] = hi;
    wp2f[(fp * 2 + 1) * 512 + wdx] = lo;
  } else if (bid < 2369) {       // w_fu frags: K=512, N=256, NT=16
    int e = (bid - 1857) * 256 + tid;
    int fp = e >> 9, wdx = e & 511;
    int l = wdx >> 3, i = wdx & 7;
    int ks = fp >> 4, n = fp & 15;
    int k = ks * 32 + 8 * (l >> 4) + i;
    int col = n * 16 + (l & 15);
    float f = w_fu[k * 256 + col];
    ushort hi = f2bf(f);
    ushort lo = f2bf(f - bf2f(hi));
    wfuf[(fp * 2 + 0) * 512 + wdx] = hi;
    wfuf[(fp * 2 + 1) * 512 + wdx] = lo;
  } else {                       // w_out frags: K=256, N=256, NT=16
    int e = (bid - 2369) * 256 + tid;
    int fp = e >> 9, wdx = e & 511;
    int l = wdx >> 3, i = wdx & 7;
    int ks = fp >> 4, n = fp & 15;
    int k = ks * 32 + 8 * (l >> 4) + i;
    int col = n * 16 + (l & 15);
    float f = w_out[k * 256 + col];
    ushort hi = f2bf(f);
    ushort lo = f2bf(f - bf2f(hi));
    woutf[(fp * 2 + 0) * 512 + wdx] = hi;
    woutf[(fp * 2 + 1) * 512 + wdx] = lo;
  }
}

// --------------------------------------------- K1: 1x1conv+BN1+ReLU -> y1g (pre-swizzled)
// MFMA order: three n-sweeps per s (dep distance 4 across a1x[n]); per-acc
// accumulation order unchanged (ah*bh, al*bh, ah*bl) -> bit-identical.
__launch_bounds__(512)
__global__ void k1_stage(const float* __restrict__ x, const ushort* __restrict__ wfB,
                         const float* __restrict__ b_sp, const float* __restrict__ g1,
                         const float* __restrict__ be1, const float* __restrict__ m1,
                         const float* __restrict__ v1, ushort* __restrict__ y1g) {
  __shared__ __align__(16) ushort xs[128 * 128];   // 32 KB swizzled tile image
  int tid = threadIdx.x;
  int bid = blockIdx.x;
  int b = bid >> 5;
  int t0 = (bid & 31) * 128;
  int l = tid & 63;
  int wid = tid >> 6;
  int lr = l & 15, lg = l >> 4;
  float sbn1[4], cbn1[4];
#pragma unroll
  for (int n = 0; n < 4; n++) {
    int o = n * 16 + lr;
    float s = g1[o] * rsqrtf(v1[o] + EPS_BN);
    sbn1[n] = s;
    cbn1[n] = (b_sp[o] - m1[o]) * s + be1[o];
  }
  const f32x4 z = {0.f, 0.f, 0.f, 0.f};
  int rowbase = wid * 16;
  const float* __restrict__ xp0 = x + ((long)b * T_LEN + t0 + rowbase + lr) * 256 + 8 * lg;
  f32x4 a1x[4];
#pragma unroll
  for (int n = 0; n < 4; n++) a1x[n] = z;
#pragma unroll 2
  for (int s = 0; s < 8; s++) {
    short8 bh[4], bl[4];
#pragma unroll
    for (int n = 0; n < 4; n++) {
      const ushort* bp = wfB + ((s * 4 + n) * 2) * 512 + l * 8;
      bh[n] = *(const short8*)bp;
      bl[n] = *(const short8*)(bp + 512);
    }
    float4 a0 = *(const float4*)(xp0 + s * 32);
    float4 a1 = *(const float4*)(xp0 + s * 32 + 4);
    float av[8] = {a0.x, a0.y, a0.z, a0.w, a1.x, a1.y, a1.z, a1.w};
    short8 ah, al;
#pragma unroll
    for (int i = 0; i < 8; i++) {
      ushort hi = f2bf(av[i]);
      ah[i] = (short)hi;
      al[i] = (short)f2bf(av[i] - bf2f(hi));
    }
#pragma unroll
    for (int n = 0; n < 4; n++)
      a1x[n] = __builtin_amdgcn_mfma_f32_16x16x32_bf16(ah, bh[n], a1x[n], 0, 0, 0);
#pragma unroll
    for (int n = 0; n < 4; n++)
      a1x[n] = __builtin_amdgcn_mfma_f32_16x16x32_bf16(al, bh[n], a1x[n], 0, 0, 0);
#pragma unroll
    for (int n = 0; n < 4; n++)
      a1x[n] = __builtin_amdgcn_mfma_f32_16x16x32_bf16(ah, bl[n], a1x[n], 0, 0, 0);
  }
#pragma unroll
  for (int r = 0; r < 4; r++) {
    int row = rowbase + lg * 4 + r;        // local row 0..127, t = t0 + row
    int sw = (row + 15) & 15;              // == (t+15)&15 since t0 % 16 == 0
#pragma unroll
    for (int n = 0; n < 4; n++) {
      float v = fmaxf(fmaf(a1x[n][r], sbn1[n], cbn1[n]), 0.f);
      ushort hi = f2bf(v);
      ushort lo = f2bf(v - bf2f(hi));
      int c = n * 16 + lr;
      int g = c >> 3;
      xs[row * 128 + (((g ^ sw) << 3) | (c & 7))] = hi;
      xs[row * 128 + ((((g + 8) ^ sw) << 3) | (c & 7))] = lo;
    }
  }
  __syncthreads();
  // drain LDS -> y1g, coalesced: 2048 uint4 total, 512 threads x 4
  long gb = ((long)b * Y1ROWS + 16 + t0) * 128;
  const uint4* __restrict__ src = (const uint4*)xs;
  uint4* __restrict__ dst = (uint4*)(y1g + gb);
  int base = tid;
#pragma unroll
  for (int i = 0; i < 4; i++)
    dst[base + i * 512] = src[base + i * 512];
}

// --------------------------------------------- K2: multi-scale conv (LDS-staged y1)
#define XR2 160   // 128 t-tile + 30 halo rows (+2 load rounding)

// Inner loop: tt-pairs (ta, ta+4), 12 MFMAs round-robin over 4 independent
// accumulators (dep distance 4). Per-accumulator order unchanged -> bit-identical.
__device__ __forceinline__ void conv_accum(
    const ushort* __restrict__ xs, const ushort* __restrict__ wfb,
    int jlo, int jhi, int SH, int h, int l,
    f32x4* __restrict__ acc0, f32x4* __restrict__ acc1) {
  int lr = l & 15, lg = l >> 4;
  int U = (jhi - jlo) * 2;   // u enumerates (j,ks) steps
  short8 c0h, c0l, c1h, c1l;
  {
    const ushort* ap = wfb + (((jlo * 2 + 0) * 4 + h * 2) * 2) * 512 + l * 8;
    c0h = *(const short8*)(ap);
    c0l = *(const short8*)(ap + 512);
    c1h = *(const short8*)(ap + 1024);
    c1l = *(const short8*)(ap + 1536);
  }
#pragma unroll 1
  for (int u = 0; u < U; u++) {
    int un = (u + 1 < U) ? u + 1 : u;
    int jn = jlo + (un >> 1), kn = un & 1;
    const ushort* apn = wfb + (((jn * 2 + kn) * 4 + h * 2) * 2) * 512 + l * 8;
    short8 n0h = *(const short8*)(apn);
    short8 n0l = *(const short8*)(apn + 512);
    short8 n1h = *(const short8*)(apn + 1024);
    short8 n1l = *(const short8*)(apn + 1536);

    int j = jlo + (u >> 1), ks = u & 1;
    int rs = j + SH;
    int gb = ks * 4 + lg;
    int sw = ((lr + rs) & 15) << 3;        // tt-invariant (tt*16 ≡ 0 mod 16)
    int ohi = (gb << 3) ^ sw;
    int olo = ((gb + 8) << 3) ^ sw;
    int rb = (lr + rs) * 128;
#pragma unroll
    for (int tp = 0; tp < 4; tp++) {
      int ba = rb + tp * 2048;             // tt = tp      -> +tp*16*128
      int bb = rb + tp * 2048 + 8192;      // tt = tp + 4
      short8 bhiA = *(const short8*)&xs[ba + ohi];
      short8 bloA = *(const short8*)&xs[ba + olo];
      short8 bhiB = *(const short8*)&xs[bb + ohi];
      short8 bloB = *(const short8*)&xs[bb + olo];
      acc0[tp]     = __builtin_amdgcn_mfma_f32_16x16x32_bf16(c0h, bhiA, acc0[tp],     0, 0, 0);
      acc1[tp]     = __builtin_amdgcn_mfma_f32_16x16x32_bf16(c1h, bhiA, acc1[tp],     0, 0, 0);
      acc0[tp + 4] = __builtin_amdgcn_mfma_f32_16x16x32_bf16(c0h, bhiB, acc0[tp + 4], 0, 0, 0);
      acc1[tp + 4] = __builtin_amdgcn_mfma_f32_16x16x32_bf16(c1h, bhiB, acc1[tp + 4], 0, 0, 0);
      acc0[tp]     = __builtin_amdgcn_mfma_f32_16x16x32_bf16(c0h, bloA, acc0[tp],     0, 0, 0);
      acc1[tp]     = __builtin_amdgcn_mfma_f32_16x16x32_bf16(c1h, bloA, acc1[tp],     0, 0, 0);
      acc0[tp + 4] = __builtin_amdgcn_mfma_f32_16x16x32_bf16(c0h, bloB, acc0[tp + 4], 0, 0, 0);
      acc1[tp + 4] = __builtin_amdgcn_mfma_f32_16x16x32_bf16(c1h, bloB, acc1[tp + 4], 0, 0, 0);
      acc0[tp]     = __builtin_amdgcn_mfma_f32_16x16x32_bf16(c0l, bhiA, acc0[tp],     0, 0, 0);
      acc1[tp]     = __builtin_amdgcn_mfma_f32_16x16x32_bf16(c1l, bhiA, acc1[tp],     0, 0, 0);
      acc0[tp + 4] = __builtin_amdgcn_mfma_f32_16x16x32_bf16(c0l, bhiB, acc0[tp + 4], 0, 0, 0);
      acc1[tp + 4] = __builtin_amdgcn_mfma_f32_16x16x32_bf16(c1l, bhiB, acc1[tp + 4], 0, 0, 0);
    }
    c0h = n0h; c0l = n0l; c1h = n1h; c1l = n1l;
  }
}

__device__ __forceinline__ void conv_epilogue(
    const f32x4* __restrict__ acc0, const f32x4* __restrict__ acc1,
    const float* __restrict__ bk, const float* __restrict__ g2,
    const float* __restrict__ be2, const float* __restrict__ m2,
    const float* __restrict__ v2,
    unsigned* __restrict__ y2p, float* __restrict__ pv,
    int b, int t0, int l, int h, int chb) {
  int lr = l & 15, lg = l >> 4;
#pragma unroll
  for (int ti = 0; ti < 2; ti++) {
#pragma unroll
    for (int r = 0; r < 4; r++) {
      int och = chb + h * 32 + ti * 16 + 4 * lg + r;
      float bias = bk[och - chb];
      float s = g2[och] * rsqrtf(v2[och] + EPS_BN);
      float sh = be2[och] - m2[och] * s;
      long idx = ((long)(b * 256 + och)) * T_LEN + t0 + lr;
      float pl[4] = {0.f, 0.f, 0.f, 0.f};
#pragma unroll
      for (int tt = 0; tt < 8; tt++) {
        float a = ti ? acc1[tt][r] : acc0[tt][r];
        float v = fmaf(fmaxf(a + bias, 0.f), s, sh);
        ushort hi = f2bf(v);
        ushort lo = f2bf(v - bf2f(hi));
        y2p[idx + tt * 16] = (unsigned)hi | ((unsigned)lo << 16);
        pl[tt >> 1] += v;
      }
#pragma unroll
      for (int j = 0; j < 4; j++) {
#pragma unroll
        for (int m = 1; m < 16; m <<= 1) pl[j] += __shfl_xor(pl[j], m);
      }
      if (lr == 0) {
#pragma unroll
        for (int j = 0; j < 4; j++)
          pv[((long)(b * 128 + (t0 >> 5) + j)) * 512 + och] = pl[j] * (1.f / 32.f);
      }
    }
  }
}

__launch_bounds__(512, 4)
__global__ void k2_convbank(const ushort* __restrict__ y1g,
    const ushort* __restrict__ wfrag,
    const float* __restrict__ bt3, const float* __restrict__ bt7,
    const float* __restrict__ bt15, const float* __restrict__ bt31,
    const float* __restrict__ g2, const float* __restrict__ be2,
    const float* __restrict__ m2, const float* __restrict__ v2,
    unsigned* __restrict__ y2p, float* __restrict__ pv) {
  __shared__ __align__(16) ushort xs[XR2 * 128];   // staged tile; reused as f32x4 red[]
  int tid = threadIdx.x;
  int bid = blockIdx.x;
  int b = bid >> 5;
  int t0 = (bid & 31) * 128;
  int l = tid & 63;
  int wid = __builtin_amdgcn_readfirstlane(tid >> 6);

  // ---- staging: 160 rows (t0-15 .. t0+144) from pre-swizzled y1g.
  {
    long gb = ((long)b * Y1ROWS + t0 + 1) * 128;
    const ushort* gpw = y1g + gb + (long)(wid * 20) * 128;
    int lo = ((l >> 4) * 128 + (l & 15) * 8);
    uint4 v[5];
#pragma unroll
    for (int i = 0; i < 5; i++)
      v[i] = *(const uint4*)(gpw + i * 512 + lo);
#pragma unroll
    for (int i = 0; i < 5; i++)
      *(uint4*)&xs[(wid * 5 + i) * 512 + l * 8] = v[i];
  }
  __syncthreads();

  // ---- conv phase
  int beta, h, jlo, jhi, role, slot;   // role: 0 direct, 1 flush, 2 add
  switch (wid) {
    case 0:  beta = 3; h = 0; jlo = 0;  jhi = 16; role = 2; slot = 0; break;
    case 1:  beta = 3; h = 0; jlo = 16; jhi = 31; role = 1; slot = 0; break;
    case 2:  beta = 3; h = 1; jlo = 0;  jhi = 16; role = 2; slot = 1; break;
    case 3:  beta = 3; h = 1; jlo = 16; jhi = 31; role = 1; slot = 1; break;
    case 4:  beta = 2; h = 0; jlo = 0;  jhi = 15; role = 0; slot = 0; break;
    case 5:  beta = 2; h = 1; jlo = 0;  jhi = 15; role = 0; slot = 0; break;
    case 6:  beta = 1; h = 0; jlo = 0;  jhi = 7;  role = 0; slot = 0; break;
    default: beta = 1; h = 1; jlo = 0;  jhi = 7;  role = 0; slot = 0; break;
  }
  const int FB[4]  = {0, 48, 160, 400};
  const int SHs[4] = {14, 12, 8, 0};
  const int CHB[4] = {0, 64, 128, 192};
  const float* bk = (beta == 0) ? bt3 : (beta == 1) ? bt7 : (beta == 2) ? bt15 : bt31;

  f32x4 acc0[8], acc1[8];
  const f32x4 z = {0.f, 0.f, 0.f, 0.f};
#pragma unroll
  for (int tt = 0; tt < 8; tt++) { acc0[tt] = z; acc1[tt] = z; }

  conv_accum(xs, wfrag + FB[beta] * 512, jlo, jhi, SHs[beta], h, l, acc0, acc1);
  if (role == 0) {
    conv_epilogue(acc0, acc1, bk, g2, be2, m2, v2, y2p, pv, b, t0, l, h, CHB[beta]);
    if (wid >= 6) {   // second pass: K=3 branch on same half
#pragma unroll
      for (int tt = 0; tt < 8; tt++) { acc0[tt] = z; acc1[tt] = z; }
      conv_accum(xs, wfrag, 0, 3, 14, h, l, acc0, acc1);
      conv_epilogue(acc0, acc1, bt3, g2, be2, m2, v2, y2p, pv, b, t0, l, h, 0);
    }
  }
  __syncthreads();                       // xs reads complete everywhere
  f32x4* red = (f32x4*)xs;
  if (role == 1) {
    f32x4* rp = red + (slot * 64 + l) * 16;
#pragma unroll
    for (int tt = 0; tt < 8; tt++) {
      rp[(tt * 2 + 0) ^ (l & 15)] = acc0[tt];
      rp[(tt * 2 + 1) ^ (l & 15)] = acc1[tt];
    }
  }
  __syncthreads();
  if (role == 2) {
    const f32x4* rp = red + (slot * 64 + l) * 16;
#pragma unroll
    for (int tt = 0; tt < 8; tt++) {
      acc0[tt] += rp[(tt * 2 + 0) ^ (l & 15)];
      acc1[tt] += rp[(tt * 2 + 1) ^ (l & 15)];
    }
    conv_epilogue(acc0, acc1, bt31, g2, be2, m2, v2, y2p, pv, b, t0, l, h, 192);
  }
}

// --------------------------------------------- K3: windowed DFT powers via MFMA
// MFMA order: three (term) sweeps over mt per n (dep distance 2); per-acc order
// unchanged -> bit-identical.
__launch_bounds__(512)
__global__ void k3_spectral(const unsigned* __restrict__ y2p,
                            const ushort* __restrict__ tabf, float* __restrict__ h0) {
  int tid = threadIdx.x;
  int l = tid & 63;
  int wid = tid >> 6;            // wave owns ch 32*wid .. +31 (2 M-tiles)
  int bid = (int)(blockIdx.x % 8u) * 124 + (int)(blockIdx.x / 8u);
  int win = bid % NWIN;
  int b = bid / NWIN;
  int t0 = win * 128;
  int lr = l & 15, lg = l >> 4;
  f32x4 acc[2][8];
  const f32x4 z = {0.f, 0.f, 0.f, 0.f};
#pragma unroll
  for (int mt = 0; mt < 2; mt++)
#pragma unroll
    for (int n = 0; n < 8; n++) acc[mt][n] = z;
  long abase = ((long)(b * 256 + wid * 32 + lr)) * T_LEN + t0 + 8 * lg;
  const unsigned* __restrict__ xp = y2p + abase;
  uint4 cA0[2], cA1[2];
#pragma unroll
  for (int mt = 0; mt < 2; mt++) {
    const uint4* p = (const uint4*)(xp + (long)mt * 16 * T_LEN);
    cA0[mt] = p[0];
    cA1[mt] = p[1];
  }
#pragma unroll 1
  for (int ks = 0; ks < 8; ks++) {
    uint4 nA0[2], nA1[2];
    if (ks < 7) {
#pragma unroll
      for (int mt = 0; mt < 2; mt++) {
        const uint4* p = (const uint4*)(xp + (long)mt * 16 * T_LEN + (ks + 1) * 32);
        nA0[mt] = p[0];
        nA1[mt] = p[1];
      }
    } else {
#pragma unroll
      for (int mt = 0; mt < 2; mt++) { nA0[mt] = cA0[mt]; nA1[mt] = cA1[mt]; }
    }
    short8 ah[2], al[2];
#pragma unroll
    for (int mt = 0; mt < 2; mt++) {
      unsigned vv[8] = {cA0[mt].x, cA0[mt].y, cA0[mt].z, cA0[mt].w,
                        cA1[mt].x, cA1[mt].y, cA1[mt].z, cA1[mt].w};
#pragma unroll
      for (int i = 0; i < 8; i++) {
        ah[mt][i] = (short)(vv[i] & 0xffffu);
        al[mt][i] = (short)(vv[i] >> 16);
      }
    }
#pragma unroll
    for (int n = 0; n < 8; n++) {
      const ushort* bp = tabf + ((ks * 8 + n) * 2) * 512 + l * 8;
      short8 bh = *(const short8*)bp;
      short8 bl = *(const short8*)(bp + 512);
#pragma unroll
      for (int mt = 0; mt < 2; mt++)
        acc[mt][n] = __builtin_amdgcn_mfma_f32_16x16x32_bf16(ah[mt], bh, acc[mt][n], 0, 0, 0);
#pragma unroll
      for (int mt = 0; mt < 2; mt++)
        acc[mt][n] = __builtin_amdgcn_mfma_f32_16x16x32_bf16(al[mt], bh, acc[mt][n], 0, 0, 0);
#pragma unroll
      for (int mt = 0; mt < 2; mt++)
        acc[mt][n] = __builtin_amdgcn_mfma_f32_16x16x32_bf16(ah[mt], bl, acc[mt][n], 0, 0, 0);
    }
#pragma unroll
    for (int mt = 0; mt < 2; mt++) { cA0[mt] = nA0[mt]; cA1[mt] = nA1[mt]; }
  }
  float wt[4][5];
#pragma unroll
  for (int n = 0; n < 4; n++) {
    int f = n * 16 + lr;
    wt[n][0] = (f <= 3)            ? 0.25f        : 0.f;
    wt[n][1] = (f >= 3 && f <= 7)  ? 0.2f         : 0.f;
    wt[n][2] = (f >= 7 && f <= 12) ? (1.f / 6.f)  : 0.f;
    wt[n][3] = (f >= 12 && f <= 29)? (1.f / 18.f) : 0.f;
    wt[n][4] = (f >= 29 && f <= 49)? (1.f / 21.f) : 0.f;
  }
  long hb = ((long)(b * NWIN + win)) * 1280;
#pragma unroll
  for (int mt = 0; mt < 2; mt++) {
#pragma unroll
    for (int r = 0; r < 4; r++) {
      float p0, p1, p2, p3;
      { float re = acc[mt][0][r], im = acc[mt][4][r]; p0 = re * re + im * im; }
      { float re = acc[mt][1][r], im = acc[mt][5][r]; p1 = re * re + im * im; }
      { float re = acc[mt][2][r], im = acc[mt][6][r]; p2 = re * re + im * im; }
      { float re = acc[mt][3][r], im = acc[mt][7][r]; p3 = re * re + im * im; }
      float s0 = p0 * wt[0][0] + p1 * wt[1][0] + p2 * wt[2][0] + p3 * wt[3][0];
      float s1 = p0 * wt[0][1] + p1 * wt[1][1] + p2 * wt[2][1] + p3 * wt[3][1];
      float s2 = p0 * wt[0][2] + p1 * wt[1][2] + p2 * wt[2][2] + p3 * wt[3][2];
      float s3 = p0 * wt[0][3] + p1 * wt[1][3] + p2 * wt[2][3] + p3 * wt[3][3];
      float s4 = p0 * wt[0][4] + p1 * wt[1][4] + p2 * wt[2][4] + p3 * wt[3][4];
#pragma unroll
      for (int m = 1; m < 16; m <<= 1) {
        s0 += __shfl_xor(s0, m);
        s1 += __shfl_xor(s1, m);
        s2 += __shfl_xor(s2, m);
        s3 += __shfl_xor(s3, m);
        s4 += __shfl_xor(s4, m);
      }
      if (lr < 5) {
        float out = lr == 0 ? s0 : lr == 1 ? s1 : lr == 2 ? s2 : lr == 3 ? s3 : s4;
        int ch = wid * 32 + mt * 16 + lg * 4 + r;
        h0[hb + lr * 256 + ch] = out;
      }
    }
  }
}

// --------------------------------------------- K4: spectral MLP via MFMA
__launch_bounds__(256)
__global__ void k4_mlp(const float* __restrict__ h0, const ushort* __restrict__ wp1f,
                       const float* __restrict__ bp1, const ushort* __restrict__ wp2f,
                       const float* __restrict__ bp2, float* __restrict__ hs) {
  __shared__ ushort t1h[16][136];
  __shared__ ushort t1l[16][136];
  int tid = threadIdx.x;
  int l = tid & 63, wid = tid >> 6;
  int lr = l & 15, lg = l >> 4;
  int r0 = blockIdx.x * 16;
  const float* __restrict__ ap0 = h0 + (long)(r0 + lr) * 1280 + 8 * lg;
  const f32x4 z = {0.f, 0.f, 0.f, 0.f};
  f32x4 acc[2];
  acc[0] = z; acc[1] = z;
#pragma unroll 2
  for (int ks = 0; ks < 40; ks++) {
    float4 a0 = *(const float4*)(ap0 + ks * 32);
    float4 a1 = *(const float4*)(ap0 + ks * 32 + 4);
    float av[8] = {a0.x, a0.y, a0.z, a0.w, a1.x, a1.y, a1.z, a1.w};
    short8 ah, al;
#pragma unroll
    for (int i = 0; i < 8; i++) {
      ushort hi = f2bf(av[i]);
      ah[i] = (short)hi;
      al[i] = (short)f2bf(av[i] - bf2f(hi));
    }
#pragma unroll
    for (int nt = 0; nt < 2; nt++) {
      const ushort* bp = wp1f + ((ks * 8 + wid * 2 + nt) * 2) * 512 + l * 8;
      short8 bh = *(const short8*)bp;
      short8 bl = *(const short8*)(bp + 512);
      acc[nt] = __builtin_amdgcn_mfma_f32_16x16x32_bf16(ah, bh, acc[nt], 0, 0, 0);
      acc[nt] = __builtin_amdgcn_mfma_f32_16x16x32_bf16(al, bh, acc[nt], 0, 0, 0);
      acc[nt] = __builtin_amdgcn_mfma_f32_16x16x32_bf16(ah, bl, acc[nt], 0, 0, 0);
    }
  }
#pragma unroll
  for (int nt = 0; nt < 2; nt++) {
    int col = (wid * 2 + nt) * 16 + lr;
    float bb = bp1[col];
#pragma unroll
    for (int r = 0; r < 4; r++) {
      int row = lg * 4 + r;
      float v = fmaxf(acc[nt][r] + bb, 0.f);
      ushort hi = f2bf(v);
      ushort lo = f2bf(v - bf2f(hi));
      t1h[row][col] = hi;
      t1l[row][col] = lo;
    }
  }
  __syncthreads();
  f32x4 a2[4];
#pragma unroll
  for (int nt = 0; nt < 4; nt++) a2[nt] = z;
#pragma unroll
  for (int ks = 0; ks < 4; ks++) {
    short8 ah = *(const short8*)&t1h[lr][ks * 32 + 8 * lg];
    short8 al = *(const short8*)&t1l[lr][ks * 32 + 8 * lg];
#pragma unroll
    for (int nt = 0; nt < 4; nt++) {
      const ushort* bp = wp2f + ((ks * 16 + wid * 4 + nt) * 2) * 512 + l * 8;
      short8 bh = *(const short8*)bp;
      short8 bl = *(const short8*)(bp + 512);
      a2[nt] = __builtin_amdgcn_mfma_f32_16x16x32_bf16(ah, bh, a2[nt], 0, 0, 0);
      a2[nt] = __builtin_amdgcn_mfma_f32_16x16x32_bf16(al, bh, a2[nt], 0, 0, 0);
      a2[nt] = __builtin_amdgcn_mfma_f32_16x16x32_bf16(ah, bl, a2[nt], 0, 0, 0);
    }
  }
#pragma unroll
  for (int nt = 0; nt < 4; nt++) {
    int col = (wid * 4 + nt) * 16 + lr;
    float bb = bp2[col];
#pragma unroll
    for (int r = 0; r < 4; r++) {
      long row = r0 + lg * 4 + r;
      hs[row * 256 + col] = a2[nt][r] + bb;
    }
  }
}

// --------------------------------------------- K5a: spec interp (3-coef) -> pv
__launch_bounds__(256)
__global__ void k5a_spec(const float* __restrict__ hs, const float4* __restrict__ jc,
                         float* __restrict__ pv) {
  int o = threadIdx.x;
  int l = blockIdx.x & 127, b = blockIdx.x >> 7;
  float4 c = jc[l];
  int j0 = __float_as_int(c.x);
  const float* __restrict__ hb = hs + (long)b * NWIN * 256;
  int i0 = j0 > 30 ? 30 : j0;
  int i1 = j0 + 1 > 30 ? 30 : j0 + 1;
  int i2 = j0 + 2 > 30 ? 30 : j0 + 2;
  float v = c.y * hb[i0 * 256 + o] + c.z * hb[i1 * 256 + o] + c.w * hb[i2 * 256 + o];
  pv[((long)(b * 128 + l)) * 512 + 256 + o] = v;
}

// --------------------------------------------- K5b: fused proj + pos + out proj via MFMA
__launch_bounds__(256)
__global__ void k5b_out(const float* __restrict__ pv, const ushort* __restrict__ wfuf,
                        const float* __restrict__ b_fu, const float* __restrict__ pos,
                        const ushort* __restrict__ woutf, const float* __restrict__ b_out,
                        float* __restrict__ out) {
  __shared__ ushort gh[32][264];
  __shared__ ushort gl[32][264];
  int tid = threadIdx.x;
  int l = tid & 63, wid = tid >> 6;
  int lr = l & 15, lg = l >> 4;
  int mt = wid & 1, nh = wid >> 1;
  int r0 = blockIdx.x * 32;
  int lbase = r0 & 127;
  const float* __restrict__ ap0 = pv + (long)(r0 + mt * 16 + lr) * 512 + 8 * lg;
  const f32x4 z = {0.f, 0.f, 0.f, 0.f};
  f32x4 acc[8];
#pragma unroll
  for (int nt = 0; nt < 8; nt++) acc[nt] = z;
#pragma unroll 1
  for (int ks = 0; ks < 16; ks++) {
    float4 a0 = *(const float4*)(ap0 + ks * 32);
    float4 a1 = *(const float4*)(ap0 + ks * 32 + 4);
    float av[8] = {a0.x, a0.y, a0.z, a0.w, a1.x, a1.y, a1.z, a1.w};
    short8 ah, al;
#pragma unroll
    for (int i = 0; i < 8; i++) {
      ushort hi = f2bf(av[i]);
      ah[i] = (short)hi;
      al[i] = (short)f2bf(av[i] - bf2f(hi));
    }
#pragma unroll
    for (int nt = 0; nt < 8; nt++) {
      const ushort* bp = wfuf + ((ks * 16 + nh * 8 + nt) * 2) * 512 + l * 8;
      short8 bh = *(const short8*)bp;
      short8 bl = *(const short8*)(bp + 512);
      acc[nt] = __builtin_amdgcn_mfma_f32_16x16x32_bf16(ah, bh, acc[nt], 0, 0, 0);
      acc[nt] = __builtin_amdgcn_mfma_f32_16x16x32_bf16(al, bh, acc[nt], 0, 0, 0);
      acc[nt] = __builtin_amdgcn_mfma_f32_16x16x32_bf16(ah, bl, acc[nt], 0, 0, 0);
    }
  }
#pragma unroll
  for (int nt = 0; nt < 8; nt++) {
    int col = (nh * 8 + nt) * 16 + lr;
    float bb = b_fu[col];
#pragma unroll
    for (int r = 0; r < 4; r++) {
      int row = mt * 16 + lg * 4 + r;
      float v = acc[nt][r] + bb + pos[(lbase + row) * 256 + col];
      ushort hi = f2bf(v);
      ushort lo = f2bf(v - bf2f(hi));
      gh[row][col] = hi;
      gl[row][col] = lo;
    }
  }
  __syncthreads();
  f32x4 a2[8];
#pragma unroll
  for (int nt = 0; nt < 8; nt++) a2[nt] = z;
#pragma unroll 1
  for (int ks = 0; ks < 8; ks++) {
    short8 ah = *(const short8*)&gh[mt * 16 + lr][ks * 32 + 8 * lg];
    short8 al = *(const short8*)&gl[mt * 16 + lr][ks * 32 + 8 * lg];
#pragma unroll
    for (int nt = 0; nt < 8; nt++) {
      const ushort* bp = woutf + ((ks * 16 + nh * 8 + nt) * 2) * 512 + l * 8;
      short8 bh = *(const short8*)bp;
      short8 bl = *(const short8*)(bp + 512);
      a2[nt] = __builtin_amdgcn_mfma_f32_16x16x32_bf16(ah, bh, a2[nt], 0, 0, 0);
      a2[nt] = __builtin_amdgcn_mfma_f32_16x16x32_bf16(al, bh, a2[nt], 0, 0, 0);
      a2[nt] = __builtin_amdgcn_mfma_f32_16x16x32_bf16(ah, bl, a2[nt], 0, 0, 0);
    }
  }
#pragma unroll
  for (int nt = 0; nt < 8; nt++) {
    int col = (nh * 8 + nt) * 16 + lr;
    float bb = b_out[col];
#pragma unroll
    for (int r = 0; r < 4; r++) {
      long row = r0 + mt * 16 + lg * 4 + r;
      out[row * 256 + col] = a2[nt][r] + bb;
    }
  }
}

// ---------------------------------------------------------------- launcher
extern "C" void kernel_launch(void* const* d_in, const int* in_sizes, int n_in,
                              void* d_out, int out_size, void* d_ws, size_t ws_size,
                              hipStream_t stream) {
  const float* x    = (const float*)d_in[0];
  const float* w_sp = (const float*)d_in[1];
  const float* b_sp = (const float*)d_in[2];
  const float* g1   = (const float*)d_in[3];
  const float* be1  = (const float*)d_in[4];
  const float* m1   = (const float*)d_in[5];
  const float* v1   = (const float*)d_in[6];
  const float* wt3  = (const float*)d_in[7];
  const float* bt3  = (const float*)d_in[8];
  const float* wt7  = (const float*)d_in[9];
  const float* bt7  = (const float*)d_in[10];
  const float* wt15 = (const float*)d_in[11];
  const float* bt15 = (const float*)d_in[12];
  const float* wt31 = (const float*)d_in[13];
  const float* bt31 = (const float*)d_in[14];
  const float* g2   = (const float*)d_in[15];
  const float* be2  = (const float*)d_in[16];
  const float* m2   = (const float*)d_in[17];
  const float* v2   = (const float*)d_in[18];
  const float* wp1  = (const float*)d_in[19];
  const float* bp1  = (const float*)d_in[20];
  const float* wp2  = (const float*)d_in[21];
  const float* bp2  = (const float*)d_in[22];
  const float* w_fu = (const float*)d_in[23];
  const float* b_fu = (const float*)d_in[24];
  const float* pos  = (const float*)d_in[25];
  const float* w_out= (const float*)d_in[26];
  const float* b_out= (const float*)d_in[27];

  unsigned* y2p = (unsigned*)d_ws;         // 33,554,432 uint (bf16 hi|lo packed)
  float* h0  = (float*)(y2p + 33554432);   //  1,269,760 f32
  float* hs  = h0 + 1269760;               //    253,952
  float* pv  = hs + 253952;                //  2,097,152
  float4* jc = (float4*)(pv + 2097152);    //        128 float4
  ushort* wfrag = (ushort*)(jc + 128);     //    458,752 ushort (conv-bank frags)
  ushort* wfB   = wfrag + 458752;          //     32,768 ushort (1x1 frags)
  ushort* tabf  = wfB + 32768;             //     65,536 ushort (DFT table frags)
  ushort* wp1f  = tabf + 65536;            //    327,680 ushort (wp1 frags)
  ushort* wp2f  = wp1f + 327680;           //     65,536 ushort (wp2 frags)
  ushort* wfuf  = wp2f + 65536;            //    262,144 ushort (w_fu frags)
  ushort* woutf = wfuf + 262144;           //    131,072 ushort (w_out frags)
  ushort* y1g   = woutf + 131072;          // 17,039,360 ushort (padded swizzled y1)

  k0_all<<<2657, 256, 0, stream>>>(wt3, wt7, wt15, wt31, w_sp, wp1, wp2, w_fu, w_out,
                                   wfrag, wfB, tabf, jc, wp1f, wp2f, wfuf, woutf, y1g);
  k1_stage<<<1024, 512, 0, stream>>>(x, wfB, b_sp, g1, be1, m1, v1, y1g);
  k2_convbank<<<1024, 512, 0, stream>>>(y1g, wfrag, bt3, bt7, bt15, bt31,
                                        g2, be2, m2, v2, y2p, pv);
  k3_spectral<<<32 * NWIN, 512, 0, stream>>>(y2p, tabf, h0);
  k4_mlp<<<62, 256, 0, stream>>>(h0, wp1f, bp1, wp2f, bp2, hs);
  k5a_spec<<<32 * 128, 256, 0, stream>>>(hs, jc, pv);
  k5b_out<<<128, 256, 0, stream>>>(pv, wfuf, b_fu, pos, woutf, b_out,
                                   (float*)d_out);
}

// Round 6
// 361.739 us; speedup vs baseline: 1.0963x; 1.0827x over previous
//
#include <hip/hip_runtime.h>
#include <hip/hip_bf16.h>

#define T_LEN 4096
#define NWIN 31
#define EPS_BN 1e-5f

typedef __attribute__((ext_vector_type(8))) short short8;
typedef __attribute__((ext_vector_type(4))) float f32x4;

__device__ __forceinline__ ushort f2bf(float x) {   // round-to-nearest-even bf16
  unsigned u = __float_as_uint(x);
  return (ushort)((u + 0x7FFFu + ((u >> 16) & 1u)) >> 16);
}
__device__ __forceinline__ float bf2f(ushort h) {
  return __uint_as_float((unsigned)h << 16);
}

// ---------------------------------------------------------------- k0: ALL init
// [0,896) conv-bank frags | [896,960) 1x1 frags | [960,1088) DFT frags |
// 1088 pool coefs | [1089,1729) wp1 frags | [1729,1857) wp2 frags |
// [1857,2369) w_fu frags | [2369,2625) w_out frags
__global__ void k0_all(const float* __restrict__ wt3, const float* __restrict__ wt7,
                       const float* __restrict__ wt15, const float* __restrict__ wt31,
                       const float* __restrict__ w_sp,
                       const float* __restrict__ wp1, const float* __restrict__ wp2,
                       const float* __restrict__ w_fu, const float* __restrict__ w_out,
                       ushort* __restrict__ wfrag, ushort* __restrict__ wfB,
                       ushort* __restrict__ tabf, float4* __restrict__ jc,
                       ushort* __restrict__ wp1f, ushort* __restrict__ wp2f,
                       ushort* __restrict__ wfuf, ushort* __restrict__ woutf) {
  int bid = blockIdx.x;
  int tid = threadIdx.x;
  if (bid < 896) {
    int e = bid * 256 + tid;
    const float* w; int K, base, eb;
    if (e < 12288)       { w = wt3;  K = 3;  base = 0;   eb = e; }
    else if (e < 40960)  { w = wt7;  K = 7;  base = 48;  eb = e - 12288; }
    else if (e < 102400) { w = wt15; K = 15; base = 160; eb = e - 40960; }
    else                 { w = wt31; K = 31; base = 400; eb = e - 102400; }
    int j = eb / 4096;  int v = eb - j * 4096;
    int ks = v >> 11;   int v2 = v & 2047;
    int tile = v2 >> 9; int wdx = v2 & 511;
    int l = wdx >> 3, i = wdx & 7;
    int o = tile * 16 + (l & 15);
    int c = ks * 32 + 8 * (l >> 4) + i;
    float f = w[(o * 64 + c) * K + j];
    ushort hi = f2bf(f);
    ushort lo = f2bf(f - bf2f(hi));
    int fragp = base + ((j * 2 + ks) * 4 + tile) * 2;
    wfrag[fragp * 512 + wdx] = hi;
    wfrag[(fragp + 1) * 512 + wdx] = lo;
  } else if (bid < 960) {
    int e = (bid - 896) * 256 + tid;
    int frag = e >> 9;
    int wdx = e & 511;
    int l = wdx >> 3, i = wdx & 7;
    int s = frag >> 2, n = frag & 3;
    int c = s * 32 + 8 * (l >> 4) + i;
    int o = n * 16 + (l & 15);
    float f = w_sp[o * 256 + c];
    ushort hi = f2bf(f);
    ushort lo = f2bf(f - bf2f(hi));
    wfB[(frag * 2 + 0) * 512 + wdx] = hi;
    wfB[(frag * 2 + 1) * 512 + wdx] = lo;
  } else if (bid < 1088) {
    int e = (bid - 960) * 256 + tid;
    int fp = e >> 9;
    int wdx = e & 511;
    int l = wdx >> 3, i = wdx & 7;
    int ks = fp >> 3, n = fp & 7;
    int k = ks * 32 + 8 * (l >> 4) + i;
    int fidx = (n & 3) * 16 + (l & 15);
    float v = 0.f;
    if (fidx < 50) {
      int f = fidx + 1;
      int ph = (f * k) & 255;
      float ang = 0.024543692606170259f * (float)ph; // 2*pi/256
      v = (n >= 4) ? sinf(ang) : cosf(ang);
    }
    ushort hi = f2bf(v);
    ushort lo = f2bf(v - bf2f(hi));
    tabf[(fp * 2 + 0) * 512 + wdx] = hi;
    tabf[(fp * 2 + 1) * 512 + wdx] = lo;
  } else if (bid == 1088) {
    if (tid < 128) {
      int l = tid;
      double cc[3] = {0.0, 0.0, 0.0};
      int j0 = -1;
      for (int t = l * 32; t < l * 32 + 32; t++) {
        double src = ((double)t + 0.5) * (31.0 / 4096.0) - 0.5;
        src = src < 0.0 ? 0.0 : (src > 30.0 ? 30.0 : src);
        int i0 = (int)src;
        if (i0 > 30) i0 = 30;
        int i1 = i0 + 1 > 30 ? 30 : i0 + 1;
        double w = src - (double)i0;
        if (j0 < 0) j0 = i0;
        cc[i0 - j0] += 1.0 - w;
        cc[i1 - j0] += w;
      }
      float4 r;
      r.x = __int_as_float(j0);
      r.y = (float)(cc[0] / 32.0);
      r.z = (float)(cc[1] / 32.0);
      r.w = (float)(cc[2] / 32.0);
      jc[l] = r;
    }
  } else if (bid < 1729) {       // wp1 frags: K=1280, N=128, NT=8
    int e = (bid - 1089) * 256 + tid;
    int fp = e >> 9, wdx = e & 511;
    int l = wdx >> 3, i = wdx & 7;
    int ks = fp >> 3, n = fp & 7;
    int k = ks * 32 + 8 * (l >> 4) + i;
    int col = n * 16 + (l & 15);
    float f = wp1[k * 128 + col];
    ushort hi = f2bf(f);
    ushort lo = f2bf(f - bf2f(hi));
    wp1f[(fp * 2 + 0) * 512 + wdx] = hi;
    wp1f[(fp * 2 + 1) * 512 + wdx] = lo;
  } else if (bid < 1857) {       // wp2 frags: K=128, N=256, NT=16
    int e = (bid - 1729) * 256 + tid;
    int fp = e >> 9, wdx = e & 511;
    int l = wdx >> 3, i = wdx & 7;
    int ks = fp >> 4, n = fp & 15;
    int k = ks * 32 + 8 * (l >> 4) + i;
    int col = n * 16 + (l & 15);
    float f = wp2[k * 256 + col];
    ushort hi = f2bf(f);
    ushort lo = f2bf(f - bf2f(hi));
    wp2f[(fp * 2 + 0) * 512 + wdx] = hi;
    wp2f[(fp * 2 + 1) * 512 + wdx] = lo;
  } else if (bid < 2369) {       // w_fu frags: K=512, N=256, NT=16
    int e = (bid - 1857) * 256 + tid;
    int fp = e >> 9, wdx = e & 511;
    int l = wdx >> 3, i = wdx & 7;
    int ks = fp >> 4, n = fp & 15;
    int k = ks * 32 + 8 * (l >> 4) + i;
    int col = n * 16 + (l & 15);
    float f = w_fu[k * 256 + col];
    ushort hi = f2bf(f);
    ushort lo = f2bf(f - bf2f(hi));
    wfuf[(fp * 2 + 0) * 512 + wdx] = hi;
    wfuf[(fp * 2 + 1) * 512 + wdx] = lo;
  } else {                       // w_out frags: K=256, N=256, NT=16
    int e = (bid - 2369) * 256 + tid;
    int fp = e >> 9, wdx = e & 511;
    int l = wdx >> 3, i = wdx & 7;
    int ks = fp >> 4, n = fp & 15;
    int k = ks * 32 + 8 * (l >> 4) + i;
    int col = n * 16 + (l & 15);
    float f = w_out[k * 256 + col];
    ushort hi = f2bf(f);
    ushort lo = f2bf(f - bf2f(hi));
    woutf[(fp * 2 + 0) * 512 + wdx] = hi;
    woutf[(fp * 2 + 1) * 512 + wdx] = lo;
  }
}

// --------------------------------------------- K2: FUSED 1x1conv+BN1+ReLU -> multi-scale conv
#define XR2 158   // 128 t-tile + 30 halo rows

// Inner loop: tt-pairs (ta, ta+4), 12 MFMAs round-robin over 4 independent
// accumulators. Per-accumulator order unchanged -> bit-identical. A-frags
// rotated one (j,ks) step ahead.
__device__ __forceinline__ void conv_accum(
    const ushort* __restrict__ xs, const ushort* __restrict__ wfb,
    int jlo, int jhi, int SH, int h, int l,
    f32x4* __restrict__ acc0, f32x4* __restrict__ acc1) {
  int lr = l & 15, lg = l >> 4;
  int U = (jhi - jlo) * 2;   // u enumerates (j,ks) steps
  short8 c0h, c0l, c1h, c1l;
  {
    const ushort* ap = wfb + (((jlo * 2 + 0) * 4 + h * 2) * 2) * 512 + l * 8;
    c0h = *(const short8*)(ap);
    c0l = *(const short8*)(ap + 512);
    c1h = *(const short8*)(ap + 1024);
    c1l = *(const short8*)(ap + 1536);
  }
#pragma unroll 1
  for (int u = 0; u < U; u++) {
    int un = (u + 1 < U) ? u + 1 : u;
    int jn = jlo + (un >> 1), kn = un & 1;
    const ushort* apn = wfb + (((jn * 2 + kn) * 4 + h * 2) * 2) * 512 + l * 8;
    short8 n0h = *(const short8*)(apn);
    short8 n0l = *(const short8*)(apn + 512);
    short8 n1h = *(const short8*)(apn + 1024);
    short8 n1l = *(const short8*)(apn + 1536);

    int j = jlo + (u >> 1), ks = u & 1;
    int rs = j + SH;
    int gb = ks * 4 + lg;
    int sw = ((lr + rs) & 15) << 3;        // tt-invariant (tt*16 ≡ 0 mod 16)
    int ohi = (gb << 3) ^ sw;
    int olo = ((gb + 8) << 3) ^ sw;
    int rb = (lr + rs) * 128;
#pragma unroll
    for (int tp = 0; tp < 4; tp++) {
      int ba = rb + tp * 2048;             // tt = tp
      int bb = rb + tp * 2048 + 8192;      // tt = tp + 4
      short8 bhiA = *(const short8*)&xs[ba + ohi];
      short8 bloA = *(const short8*)&xs[ba + olo];
      short8 bhiB = *(const short8*)&xs[bb + ohi];
      short8 bloB = *(const short8*)&xs[bb + olo];
      acc0[tp]     = __builtin_amdgcn_mfma_f32_16x16x32_bf16(c0h, bhiA, acc0[tp],     0, 0, 0);
      acc1[tp]     = __builtin_amdgcn_mfma_f32_16x16x32_bf16(c1h, bhiA, acc1[tp],     0, 0, 0);
      acc0[tp + 4] = __builtin_amdgcn_mfma_f32_16x16x32_bf16(c0h, bhiB, acc0[tp + 4], 0, 0, 0);
      acc1[tp + 4] = __builtin_amdgcn_mfma_f32_16x16x32_bf16(c1h, bhiB, acc1[tp + 4], 0, 0, 0);
      acc0[tp]     = __builtin_amdgcn_mfma_f32_16x16x32_bf16(c0h, bloA, acc0[tp],     0, 0, 0);
      acc1[tp]     = __builtin_amdgcn_mfma_f32_16x16x32_bf16(c1h, bloA, acc1[tp],     0, 0, 0);
      acc0[tp + 4] = __builtin_amdgcn_mfma_f32_16x16x32_bf16(c0h, bloB, acc0[tp + 4], 0, 0, 0);
      acc1[tp + 4] = __builtin_amdgcn_mfma_f32_16x16x32_bf16(c1h, bloB, acc1[tp + 4], 0, 0, 0);
      acc0[tp]     = __builtin_amdgcn_mfma_f32_16x16x32_bf16(c0l, bhiA, acc0[tp],     0, 0, 0);
      acc1[tp]     = __builtin_amdgcn_mfma_f32_16x16x32_bf16(c1l, bhiA, acc1[tp],     0, 0, 0);
      acc0[tp + 4] = __builtin_amdgcn_mfma_f32_16x16x32_bf16(c0l, bhiB, acc0[tp + 4], 0, 0, 0);
      acc1[tp + 4] = __builtin_amdgcn_mfma_f32_16x16x32_bf16(c1l, bhiB, acc1[tp + 4], 0, 0, 0);
    }
    c0h = n0h; c0l = n0l; c1h = n1h; c1l = n1l;
  }
}

__device__ __forceinline__ void conv_epilogue(
    const f32x4* __restrict__ acc0, const f32x4* __restrict__ acc1,
    const float* __restrict__ bk, const float* __restrict__ g2,
    const float* __restrict__ be2, const float* __restrict__ m2,
    const float* __restrict__ v2,
    unsigned* __restrict__ y2p, float* __restrict__ pv,
    int b, int t0, int l, int h, int chb) {
  int lr = l & 15, lg = l >> 4;
#pragma unroll
  for (int ti = 0; ti < 2; ti++) {
#pragma unroll
    for (int r = 0; r < 4; r++) {
      int och = chb + h * 32 + ti * 16 + 4 * lg + r;
      float bias = bk[och - chb];
      float s = g2[och] * rsqrtf(v2[och] + EPS_BN);
      float sh = be2[och] - m2[och] * s;
      long idx = ((long)(b * 256 + och)) * T_LEN + t0 + lr;
      float pl[4] = {0.f, 0.f, 0.f, 0.f};
#pragma unroll
      for (int tt = 0; tt < 8; tt++) {
        float a = ti ? acc1[tt][r] : acc0[tt][r];
        float v = fmaf(fmaxf(a + bias, 0.f), s, sh);
        ushort hi = f2bf(v);
        ushort lo = f2bf(v - bf2f(hi));
        y2p[idx + tt * 16] = (unsigned)hi | ((unsigned)lo << 16);
        pl[tt >> 1] += v;
      }
#pragma unroll
      for (int j = 0; j < 4; j++) {
#pragma unroll
        for (int m = 1; m < 16; m <<= 1) pl[j] += __shfl_xor(pl[j], m);
      }
      if (lr == 0) {
#pragma unroll
        for (int j = 0; j < 4; j++)
          pv[((long)(b * 128 + (t0 >> 5) + j)) * 512 + och] = pl[j] * (1.f / 32.f);
      }
    }
  }
}

__launch_bounds__(512, 4)
__global__ void k2_convbank(const float* __restrict__ x,
    const ushort* __restrict__ wfB,
    const float* __restrict__ b_sp, const float* __restrict__ g1,
    const float* __restrict__ be1, const float* __restrict__ m1,
    const float* __restrict__ v1,
    const ushort* __restrict__ wfrag,
    const float* __restrict__ bt3, const float* __restrict__ bt7,
    const float* __restrict__ bt15, const float* __restrict__ bt31,
    const float* __restrict__ g2, const float* __restrict__ be2,
    const float* __restrict__ m2, const float* __restrict__ v2,
    unsigned* __restrict__ y2p, float* __restrict__ pv) {
  __shared__ __align__(16) ushort xs[XR2 * 128];   // staged tile; reused as f32x4 red[]
  int tid = threadIdx.x;
  int bid = blockIdx.x;
  int b = bid >> 5;
  int t0 = (bid & 31) * 128;
  int l = tid & 63;
  int wid = __builtin_amdgcn_readfirstlane(tid >> 6);
  int lr = l & 15, lg = l >> 4;

  // ---- staging: compute y1 rows into swizzled xs (bit-identical recipe;
  // MFMA order = three n-sweeps, per-acc order preserved).
  // tiles 0..7 -> waves 0..7; extra tiles 8,9 -> lightest conv waves 6,7
  {
    float sbn1[4], cbn1[4];
#pragma unroll
    for (int n = 0; n < 4; n++) {
      int o = n * 16 + lr;
      float s = g1[o] * rsqrtf(v1[o] + EPS_BN);
      sbn1[n] = s;
      cbn1[n] = (b_sp[o] - m1[o]) * s + be1[o];
    }
    const f32x4 z = {0.f, 0.f, 0.f, 0.f};
#pragma unroll 1
    for (int mt = wid; mt < 10; mt += (wid >= 6 ? 2 : 16)) {
      int rowbase = mt * 16;
      long tl = (long)t0 - 15 + rowbase + lr;  // A-load row
      long tc = tl < 0 ? 0 : (tl > T_LEN - 1 ? T_LEN - 1 : tl);
      const float* __restrict__ xp0 = x + ((long)b * T_LEN + tc) * 256 + 8 * lg;
      f32x4 a1x[4];
#pragma unroll
      for (int n = 0; n < 4; n++) a1x[n] = z;
#pragma unroll 2
      for (int s = 0; s < 8; s++) {
        short8 bh[4], bl[4];
#pragma unroll
        for (int n = 0; n < 4; n++) {
          const ushort* bp = wfB + ((s * 4 + n) * 2) * 512 + l * 8;
          bh[n] = *(const short8*)bp;
          bl[n] = *(const short8*)(bp + 512);
        }
        float4 a0 = *(const float4*)(xp0 + s * 32);
        float4 a1 = *(const float4*)(xp0 + s * 32 + 4);
        float av[8] = {a0.x, a0.y, a0.z, a0.w, a1.x, a1.y, a1.z, a1.w};
        short8 ah, al;
#pragma unroll
        for (int i = 0; i < 8; i++) {
          ushort hi = f2bf(av[i]);
          ah[i] = (short)hi;
          al[i] = (short)f2bf(av[i] - bf2f(hi));
        }
#pragma unroll
        for (int n = 0; n < 4; n++)
          a1x[n] = __builtin_amdgcn_mfma_f32_16x16x32_bf16(ah, bh[n], a1x[n], 0, 0, 0);
#pragma unroll
        for (int n = 0; n < 4; n++)
          a1x[n] = __builtin_amdgcn_mfma_f32_16x16x32_bf16(al, bh[n], a1x[n], 0, 0, 0);
#pragma unroll
        for (int n = 0; n < 4; n++)
          a1x[n] = __builtin_amdgcn_mfma_f32_16x16x32_bf16(ah, bl[n], a1x[n], 0, 0, 0);
      }
#pragma unroll
      for (int r = 0; r < 4; r++) {
        int row = rowbase + lg * 4 + r;
        int t = t0 - 15 + row;
        if (row < XR2) {
          int sw = row & 15;
          bool tv = (t >= 0 && t < T_LEN);
#pragma unroll
          for (int n = 0; n < 4; n++) {
            float v = tv ? fmaxf(fmaf(a1x[n][r], sbn1[n], cbn1[n]), 0.f) : 0.f;
            ushort hi = f2bf(v);
            ushort lo = f2bf(v - bf2f(hi));
            int c = n * 16 + lr;
            int g = c >> 3;
            xs[row * 128 + ((g ^ sw) << 3) + (c & 7)] = hi;
            xs[row * 128 + (((g + 8) ^ sw) << 3) + (c & 7)] = lo;
          }
        }
      }
    }
  }
  __syncthreads();

  // ---- conv phase
  int beta, h, jlo, jhi, role, slot;   // role: 0 direct, 1 flush, 2 add
  switch (wid) {
    case 0:  beta = 3; h = 0; jlo = 0;  jhi = 16; role = 2; slot = 0; break;
    case 1:  beta = 3; h = 0; jlo = 16; jhi = 31; role = 1; slot = 0; break;
    case 2:  beta = 3; h = 1; jlo = 0;  jhi = 16; role = 2; slot = 1; break;
    case 3:  beta = 3; h = 1; jlo = 16; jhi = 31; role = 1; slot = 1; break;
    case 4:  beta = 2; h = 0; jlo = 0;  jhi = 15; role = 0; slot = 0; break;
    case 5:  beta = 2; h = 1; jlo = 0;  jhi = 15; role = 0; slot = 0; break;
    case 6:  beta = 1; h = 0; jlo = 0;  jhi = 7;  role = 0; slot = 0; break;
    default: beta = 1; h = 1; jlo = 0;  jhi = 7;  role = 0; slot = 0; break;
  }
  const int FB[4]  = {0, 48, 160, 400};
  const int SHs[4] = {14, 12, 8, 0};
  const int CHB[4] = {0, 64, 128, 192};
  const float* bk = (beta == 0) ? bt3 : (beta == 1) ? bt7 : (beta == 2) ? bt15 : bt31;

  f32x4 acc0[8], acc1[8];
  const f32x4 z = {0.f, 0.f, 0.f, 0.f};
#pragma unroll
  for (int tt = 0; tt < 8; tt++) { acc0[tt] = z; acc1[tt] = z; }

  conv_accum(xs, wfrag + FB[beta] * 512, jlo, jhi, SHs[beta], h, l, acc0, acc1);
  if (role == 0) {
    conv_epilogue(acc0, acc1, bk, g2, be2, m2, v2, y2p, pv, b, t0, l, h, CHB[beta]);
    if (wid >= 6) {   // second pass: K=3 branch on same half
#pragma unroll
      for (int tt = 0; tt < 8; tt++) { acc0[tt] = z; acc1[tt] = z; }
      conv_accum(xs, wfrag, 0, 3, 14, h, l, acc0, acc1);
      conv_epilogue(acc0, acc1, bt3, g2, be2, m2, v2, y2p, pv, b, t0, l, h, 0);
    }
  }
  __syncthreads();                       // xs reads complete everywhere
  f32x4* red = (f32x4*)xs;
  if (role == 1) {
    f32x4* rp = red + (slot * 64 + l) * 16;
#pragma unroll
    for (int tt = 0; tt < 8; tt++) {
      rp[(tt * 2 + 0) ^ (l & 15)] = acc0[tt];
      rp[(tt * 2 + 1) ^ (l & 15)] = acc1[tt];
    }
  }
  __syncthreads();
  if (role == 2) {
    const f32x4* rp = red + (slot * 64 + l) * 16;
#pragma unroll
    for (int tt = 0; tt < 8; tt++) {
      acc0[tt] += rp[(tt * 2 + 0) ^ (l & 15)];
      acc1[tt] += rp[(tt * 2 + 1) ^ (l & 15)];
    }
    conv_epilogue(acc0, acc1, bt31, g2, be2, m2, v2, y2p, pv, b, t0, l, h, 192);
  }
}

// --------------------------------------------- K3: windowed DFT powers via MFMA
__launch_bounds__(512)
__global__ void k3_spectral(const unsigned* __restrict__ y2p,
                            const ushort* __restrict__ tabf, float* __restrict__ h0) {
  int tid = threadIdx.x;
  int l = tid & 63;
  int wid = tid >> 6;            // wave owns ch 32*wid .. +31 (2 M-tiles)
  int bid = (int)(blockIdx.x % 8u) * 124 + (int)(blockIdx.x / 8u);
  int win = bid % NWIN;
  int b = bid / NWIN;
  int t0 = win * 128;
  int lr = l & 15, lg = l >> 4;
  f32x4 acc[2][8];
  const f32x4 z = {0.f, 0.f, 0.f, 0.f};
#pragma unroll
  for (int mt = 0; mt < 2; mt++)
#pragma unroll
    for (int n = 0; n < 8; n++) acc[mt][n] = z;
  long abase = ((long)(b * 256 + wid * 32 + lr)) * T_LEN + t0 + 8 * lg;
  const unsigned* __restrict__ xp = y2p + abase;
  uint4 cA0[2], cA1[2];
#pragma unroll
  for (int mt = 0; mt < 2; mt++) {
    const uint4* p = (const uint4*)(xp + (long)mt * 16 * T_LEN);
    cA0[mt] = p[0];
    cA1[mt] = p[1];
  }
#pragma unroll 1
  for (int ks = 0; ks < 8; ks++) {
    uint4 nA0[2], nA1[2];
    if (ks < 7) {
#pragma unroll
      for (int mt = 0; mt < 2; mt++) {
        const uint4* p = (const uint4*)(xp + (long)mt * 16 * T_LEN + (ks + 1) * 32);
        nA0[mt] = p[0];
        nA1[mt] = p[1];
      }
    } else {
#pragma unroll
      for (int mt = 0; mt < 2; mt++) { nA0[mt] = cA0[mt]; nA1[mt] = cA1[mt]; }
    }
    short8 ah[2], al[2];
#pragma unroll
    for (int mt = 0; mt < 2; mt++) {
      unsigned vv[8] = {cA0[mt].x, cA0[mt].y, cA0[mt].z, cA0[mt].w,
                        cA1[mt].x, cA1[mt].y, cA1[mt].z, cA1[mt].w};
#pragma unroll
      for (int i = 0; i < 8; i++) {
        ah[mt][i] = (short)(vv[i] & 0xffffu);
        al[mt][i] = (short)(vv[i] >> 16);
      }
    }
#pragma unroll
    for (int n = 0; n < 8; n++) {
      const ushort* bp = tabf + ((ks * 8 + n) * 2) * 512 + l * 8;
      short8 bh = *(const short8*)bp;
      short8 bl = *(const short8*)(bp + 512);
#pragma unroll
      for (int mt = 0; mt < 2; mt++)
        acc[mt][n] = __builtin_amdgcn_mfma_f32_16x16x32_bf16(ah[mt], bh, acc[mt][n], 0, 0, 0);
#pragma unroll
      for (int mt = 0; mt < 2; mt++)
        acc[mt][n] = __builtin_amdgcn_mfma_f32_16x16x32_bf16(al[mt], bh, acc[mt][n], 0, 0, 0);
#pragma unroll
      for (int mt = 0; mt < 2; mt++)
        acc[mt][n] = __builtin_amdgcn_mfma_f32_16x16x32_bf16(ah[mt], bl, acc[mt][n], 0, 0, 0);
    }
#pragma unroll
    for (int mt = 0; mt < 2; mt++) { cA0[mt] = nA0[mt]; cA1[mt] = nA1[mt]; }
  }
  float wt[4][5];
#pragma unroll
  for (int n = 0; n < 4; n++) {
    int f = n * 16 + lr;
    wt[n][0] = (f <= 3)            ? 0.25f        : 0.f;
    wt[n][1] = (f >= 3 && f <= 7)  ? 0.2f         : 0.f;
    wt[n][2] = (f >= 7 && f <= 12) ? (1.f / 6.f)  : 0.f;
    wt[n][3] = (f >= 12 && f <= 29)? (1.f / 18.f) : 0.f;
    wt[n][4] = (f >= 29 && f <= 49)? (1.f / 21.f) : 0.f;
  }
  long hb = ((long)(b * NWIN + win)) * 1280;
#pragma unroll
  for (int mt = 0; mt < 2; mt++) {
#pragma unroll
    for (int r = 0; r < 4; r++) {
      float p0, p1, p2, p3;
      { float re = acc[mt][0][r], im = acc[mt][4][r]; p0 = re * re + im * im; }
      { float re = acc[mt][1][r], im = acc[mt][5][r]; p1 = re * re + im * im; }
      { float re = acc[mt][2][r], im = acc[mt][6][r]; p2 = re * re + im * im; }
      { float re = acc[mt][3][r], im = acc[mt][7][r]; p3 = re * re + im * im; }
      float s0 = p0 * wt[0][0] + p1 * wt[1][0] + p2 * wt[2][0] + p3 * wt[3][0];
      float s1 = p0 * wt[0][1] + p1 * wt[1][1] + p2 * wt[2][1] + p3 * wt[3][1];
      float s2 = p0 * wt[0][2] + p1 * wt[1][2] + p2 * wt[2][2] + p3 * wt[3][2];
      float s3 = p0 * wt[0][3] + p1 * wt[1][3] + p2 * wt[2][3] + p3 * wt[3][3];
      float s4 = p0 * wt[0][4] + p1 * wt[1][4] + p2 * wt[2][4] + p3 * wt[3][4];
#pragma unroll
      for (int m = 1; m < 16; m <<= 1) {
        s0 += __shfl_xor(s0, m);
        s1 += __shfl_xor(s1, m);
        s2 += __shfl_xor(s2, m);
        s3 += __shfl_xor(s3, m);
        s4 += __shfl_xor(s4, m);
      }
      if (lr < 5) {
        float out = lr == 0 ? s0 : lr == 1 ? s1 : lr == 2 ? s2 : lr == 3 ? s3 : s4;
        int ch = wid * 32 + mt * 16 + lg * 4 + r;
        h0[hb + lr * 256 + ch] = out;
      }
    }
  }
}

// --------------------------------------------- K4: spectral MLP via MFMA
__launch_bounds__(256)
__global__ void k4_mlp(const float* __restrict__ h0, const ushort* __restrict__ wp1f,
                       const float* __restrict__ bp1, const ushort* __restrict__ wp2f,
                       const float* __restrict__ bp2, float* __restrict__ hs) {
  __shared__ ushort t1h[16][136];
  __shared__ ushort t1l[16][136];
  int tid = threadIdx.x;
  int l = tid & 63, wid = tid >> 6;
  int lr = l & 15, lg = l >> 4;
  int r0 = blockIdx.x * 16;
  const float* __restrict__ ap0 = h0 + (long)(r0 + lr) * 1280 + 8 * lg;
  const f32x4 z = {0.f, 0.f, 0.f, 0.f};
  f32x4 acc[2];
  acc[0] = z; acc[1] = z;
#pragma unroll 2
  for (int ks = 0; ks < 40; ks++) {
    float4 a0 = *(const float4*)(ap0 + ks * 32);
    float4 a1 = *(const float4*)(ap0 + ks * 32 + 4);
    float av[8] = {a0.x, a0.y, a0.z, a0.w, a1.x, a1.y, a1.z, a1.w};
    short8 ah, al;
#pragma unroll
    for (int i = 0; i < 8; i++) {
      ushort hi = f2bf(av[i]);
      ah[i] = (short)hi;
      al[i] = (short)f2bf(av[i] - bf2f(hi));
    }
#pragma unroll
    for (int nt = 0; nt < 2; nt++) {
      const ushort* bp = wp1f + ((ks * 8 + wid * 2 + nt) * 2) * 512 + l * 8;
      short8 bh = *(const short8*)bp;
      short8 bl = *(const short8*)(bp + 512);
      acc[nt] = __builtin_amdgcn_mfma_f32_16x16x32_bf16(ah, bh, acc[nt], 0, 0, 0);
      acc[nt] = __builtin_amdgcn_mfma_f32_16x16x32_bf16(al, bh, acc[nt], 0, 0, 0);
      acc[nt] = __builtin_amdgcn_mfma_f32_16x16x32_bf16(ah, bl, acc[nt], 0, 0, 0);
    }
  }
#pragma unroll
  for (int nt = 0; nt < 2; nt++) {
    int col = (wid * 2 + nt) * 16 + lr;
    float bb = bp1[col];
#pragma unroll
    for (int r = 0; r < 4; r++) {
      int row = lg * 4 + r;
      float v = fmaxf(acc[nt][r] + bb, 0.f);
      ushort hi = f2bf(v);
      ushort lo = f2bf(v - bf2f(hi));
      t1h[row][col] = hi;
      t1l[row][col] = lo;
    }
  }
  __syncthreads();
  f32x4 a2[4];
#pragma unroll
  for (int nt = 0; nt < 4; nt++) a2[nt] = z;
#pragma unroll
  for (int ks = 0; ks < 4; ks++) {
    short8 ah = *(const short8*)&t1h[lr][ks * 32 + 8 * lg];
    short8 al = *(const short8*)&t1l[lr][ks * 32 + 8 * lg];
#pragma unroll
    for (int nt = 0; nt < 4; nt++) {
      const ushort* bp = wp2f + ((ks * 16 + wid * 4 + nt) * 2) * 512 + l * 8;
      short8 bh = *(const short8*)bp;
      short8 bl = *(const short8*)(bp + 512);
      a2[nt] = __builtin_amdgcn_mfma_f32_16x16x32_bf16(ah, bh, a2[nt], 0, 0, 0);
      a2[nt] = __builtin_amdgcn_mfma_f32_16x16x32_bf16(al, bh, a2[nt], 0, 0, 0);
      a2[nt] = __builtin_amdgcn_mfma_f32_16x16x32_bf16(ah, bl, a2[nt], 0, 0, 0);
    }
  }
#pragma unroll
  for (int nt = 0; nt < 4; nt++) {
    int col = (wid * 4 + nt) * 16 + lr;
    float bb = bp2[col];
#pragma unroll
    for (int r = 0; r < 4; r++) {
      long row = r0 + lg * 4 + r;
      hs[row * 256 + col] = a2[nt][r] + bb;
    }
  }
}

// --------------------------------------------- K5a: spec interp (3-coef) -> pv
__launch_bounds__(256)
__global__ void k5a_spec(const float* __restrict__ hs, const float4* __restrict__ jc,
                         float* __restrict__ pv) {
  int o = threadIdx.x;
  int l = blockIdx.x & 127, b = blockIdx.x >> 7;
  float4 c = jc[l];
  int j0 = __float_as_int(c.x);
  const float* __restrict__ hb = hs + (long)b * NWIN * 256;
  int i0 = j0 > 30 ? 30 : j0;
  int i1 = j0 + 1 > 30 ? 30 : j0 + 1;
  int i2 = j0 + 2 > 30 ? 30 : j0 + 2;
  float v = c.y * hb[i0 * 256 + o] + c.z * hb[i1 * 256 + o] + c.w * hb[i2 * 256 + o];
  pv[((long)(b * 128 + l)) * 512 + 256 + o] = v;
}

// --------------------------------------------- K5b: fused proj + pos + out proj via MFMA
__launch_bounds__(256)
__global__ void k5b_out(const float* __restrict__ pv, const ushort* __restrict__ wfuf,
                        const float* __restrict__ b_fu, const float* __restrict__ pos,
                        const ushort* __restrict__ woutf, const float* __restrict__ b_out,
                        float* __restrict__ out) {
  __shared__ ushort gh[32][264];
  __shared__ ushort gl[32][264];
  int tid = threadIdx.x;
  int l = tid & 63, wid = tid >> 6;
  int lr = l & 15, lg = l >> 4;
  int mt = wid & 1, nh = wid >> 1;
  int r0 = blockIdx.x * 32;
  int lbase = r0 & 127;
  const float* __restrict__ ap0 = pv + (long)(r0 + mt * 16 + lr) * 512 + 8 * lg;
  const f32x4 z = {0.f, 0.f, 0.f, 0.f};
  f32x4 acc[8];
#pragma unroll
  for (int nt = 0; nt < 8; nt++) acc[nt] = z;
#pragma unroll 1
  for (int ks = 0; ks < 16; ks++) {
    float4 a0 = *(const float4*)(ap0 + ks * 32);
    float4 a1 = *(const float4*)(ap0 + ks * 32 + 4);
    float av[8] = {a0.x, a0.y, a0.z, a0.w, a1.x, a1.y, a1.z, a1.w};
    short8 ah, al;
#pragma unroll
    for (int i = 0; i < 8; i++) {
      ushort hi = f2bf(av[i]);
      ah[i] = (short)hi;
      al[i] = (short)f2bf(av[i] - bf2f(hi));
    }
#pragma unroll
    for (int nt = 0; nt < 8; nt++) {
      const ushort* bp = wfuf + ((ks * 16 + nh * 8 + nt) * 2) * 512 + l * 8;
      short8 bh = *(const short8*)bp;
      short8 bl = *(const short8*)(bp + 512);
      acc[nt] = __builtin_amdgcn_mfma_f32_16x16x32_bf16(ah, bh, acc[nt], 0, 0, 0);
      acc[nt] = __builtin_amdgcn_mfma_f32_16x16x32_bf16(al, bh, acc[nt], 0, 0, 0);
      acc[nt] = __builtin_amdgcn_mfma_f32_16x16x32_bf16(ah, bl, acc[nt], 0, 0, 0);
    }
  }
#pragma unroll
  for (int nt = 0; nt < 8; nt++) {
    int col = (nh * 8 + nt) * 16 + lr;
    float bb = b_fu[col];
#pragma unroll
    for (int r = 0; r < 4; r++) {
      int row = mt * 16 + lg * 4 + r;
      float v = acc[nt][r] + bb + pos[(lbase + row) * 256 + col];
      ushort hi = f2bf(v);
      ushort lo = f2bf(v - bf2f(hi));
      gh[row][col] = hi;
      gl[row][col] = lo;
    }
  }
  __syncthreads();
  f32x4 a2[8];
#pragma unroll
  for (int nt = 0; nt < 8; nt++) a2[nt] = z;
#pragma unroll 1
  for (int ks = 0; ks < 8; ks++) {
    short8 ah = *(const short8*)&gh[mt * 16 + lr][ks * 32 + 8 * lg];
    short8 al = *(const short8*)&gl[mt * 16 + lr][ks * 32 + 8 * lg];
#pragma unroll
    for (int nt = 0; nt < 8; nt++) {
      const ushort* bp = woutf + ((ks * 16 + nh * 8 + nt) * 2) * 512 + l * 8;
      short8 bh = *(const short8*)bp;
      short8 bl = *(const short8*)(bp + 512);
      a2[nt] = __builtin_amdgcn_mfma_f32_16x16x32_bf16(ah, bh, a2[nt], 0, 0, 0);
      a2[nt] = __builtin_amdgcn_mfma_f32_16x16x32_bf16(al, bh, a2[nt], 0, 0, 0);
      a2[nt] = __builtin_amdgcn_mfma_f32_16x16x32_bf16(ah, bl, a2[nt], 0, 0, 0);
    }
  }
#pragma unroll
  for (int nt = 0; nt < 8; nt++) {
    int col = (nh * 8 + nt) * 16 + lr;
    float bb = b_out[col];
#pragma unroll
    for (int r = 0; r < 4; r++) {
      long row = r0 + mt * 16 + lg * 4 + r;
      out[row * 256 + col] = a2[nt][r] + bb;
    }
  }
}

// ---------------------------------------------------------------- launcher
extern "C" void kernel_launch(void* const* d_in, const int* in_sizes, int n_in,
                              void* d_out, int out_size, void* d_ws, size_t ws_size,
                              hipStream_t stream) {
  const float* x    = (const float*)d_in[0];
  const float* w_sp = (const float*)d_in[1];
  const float* b_sp = (const float*)d_in[2];
  const float* g1   = (const float*)d_in[3];
  const float* be1  = (const float*)d_in[4];
  const float* m1   = (const float*)d_in[5];
  const float* v1   = (const float*)d_in[6];
  const float* wt3  = (const float*)d_in[7];
  const float* bt3  = (const float*)d_in[8];
  const float* wt7  = (const float*)d_in[9];
  const float* bt7  = (const float*)d_in[10];
  const float* wt15 = (const float*)d_in[11];
  const float* bt15 = (const float*)d_in[12];
  const float* wt31 = (const float*)d_in[13];
  const float* bt31 = (const float*)d_in[14];
  const float* g2   = (const float*)d_in[15];
  const float* be2  = (const float*)d_in[16];
  const float* m2   = (const float*)d_in[17];
  const float* v2   = (const float*)d_in[18];
  const float* wp1  = (const float*)d_in[19];
  const float* bp1  = (const float*)d_in[20];
  const float* wp2  = (const float*)d_in[21];
  const float* bp2  = (const float*)d_in[22];
  const float* w_fu = (const float*)d_in[23];
  const float* b_fu = (const float*)d_in[24];
  const float* pos  = (const float*)d_in[25];
  const float* w_out= (const float*)d_in[26];
  const float* b_out= (const float*)d_in[27];

  unsigned* y2p = (unsigned*)d_ws;         // 33,554,432 uint (bf16 hi|lo packed)
  float* h0  = (float*)(y2p + 33554432);   //  1,269,760 f32
  float* hs  = h0 + 1269760;               //    253,952
  float* pv  = hs + 253952;                //  2,097,152
  float4* jc = (float4*)(pv + 2097152);    //        128 float4
  ushort* wfrag = (ushort*)(jc + 128);     //    458,752 ushort (conv-bank frags)
  ushort* wfB   = wfrag + 458752;          //     32,768 ushort (1x1 frags)
  ushort* tabf  = wfB + 32768;             //     65,536 ushort (DFT table frags)
  ushort* wp1f  = tabf + 65536;            //    327,680 ushort (wp1 frags)
  ushort* wp2f  = wp1f + 327680;           //     65,536 ushort (wp2 frags)
  ushort* wfuf  = wp2f + 65536;            //    262,144 ushort (w_fu frags)
  ushort* woutf = wfuf + 262144;           //    131,072 ushort (w_out frags)

  k0_all<<<2625, 256, 0, stream>>>(wt3, wt7, wt15, wt31, w_sp, wp1, wp2, w_fu, w_out,
                                   wfrag, wfB, tabf, jc, wp1f, wp2f, wfuf, woutf);
  k2_convbank<<<1024, 512, 0, stream>>>(x, wfB, b_sp, g1, be1, m1, v1,
                                        wfrag, bt3, bt7, bt15, bt31,
                                        g2, be2, m2, v2, y2p, pv);
  k3_spectral<<<32 * NWIN, 512, 0, stream>>>(y2p, tabf, h0);
  k4_mlp<<<62, 256, 0, stream>>>(h0, wp1f, bp1, wp2f, bp2, hs);
  k5a_spec<<<32 * 128, 256, 0, stream>>>(hs, jc, pv);
  k5b_out<<<128, 256, 0, stream>>>(pv, wfuf, b_fu, pos, woutf, b_out,
                                   (float*)d_out);
}